// Round 3
// baseline (397.963 us; speedup 1.0000x reference)
//
#include <hip/hip_runtime.h>
#include <math.h>

// ---------------------------------------------------------------------------
// DiffHead, MFMA edition, round 9: pin waves/EU to stop the 64-VGPR clamp.
//   r7/r8 showed the backend allocates attn_mfma at 64 VGPRs regardless of
//   __launch_bounds__ second arg (it targets 8 waves/EU = 2 blocks/CU,
//   ignoring that 117KB LDS already limits us to 1 block/CU) -> ~49MB of
//   scratch spill per launch (WRITE_SIZE 57MB), 85% stall.
//   Fix: __attribute__((amdgpu_waves_per_eu(4,4))) on attn_mfma. min=max=4
//   waves/EU = 16 waves/CU = exactly our LDS-limited occupancy; VGPR budget
//   becomes 512/4 = 128, the ~100-VGPR body fits with no spill.
// Everything else identical to r8.
// Math: fill=1e-9 => exp(fill*scale)==1.0f -> masked tail closed-form via V
//   prefix sums; padded rows closed form; fixed softmax shift m=0.
// MFMA 16x16x32_bf16 layouts: A/B lane: m/n=lane&15, k=quad*8+j (16B contig);
//   C/D: col=lane&15, row=quad*4+reg.
// ---------------------------------------------------------------------------

#define T_SEQ 2048
#define NB 8
#define CDIM 1024
#define HS 128

constexpr float SCALE = 0.08838834764831845f;   // 128^-0.5

typedef float f32x4 __attribute__((ext_vector_type(4)));
typedef __bf16 bf16x8 __attribute__((ext_vector_type(8)));
typedef unsigned int u32;

#define MFMA16 __builtin_amdgcn_mfma_f32_16x16x32_bf16

__device__ __forceinline__ void gld16(const void* g, void* l) {
  __builtin_amdgcn_global_load_lds(
      (const __attribute__((address_space(1))) u32*)g,
      (__attribute__((address_space(3))) u32*)l, 16, 0, 0);
}

__device__ __forceinline__ bf16x8 cvt8(f32x4 lo, f32x4 hi) {
  bf16x8 r;
  r[0] = (__bf16)lo.x; r[1] = (__bf16)lo.y; r[2] = (__bf16)lo.z; r[3] = (__bf16)lo.w;
  r[4] = (__bf16)hi.x; r[5] = (__bf16)hi.y; r[6] = (__bf16)hi.z; r[7] = (__bf16)hi.w;
  return r;
}

// --------------------------- lambda = exp(lq1.lk1) - exp(lq2.lk2) + 0.8 -----
__global__ __launch_bounds__(128) void lambda_kernel(
    const float* __restrict__ lq1, const float* __restrict__ lk1,
    const float* __restrict__ lq2, const float* __restrict__ lk2,
    float* __restrict__ lbd) {
  __shared__ float r1[128], r2[128];
  int t = threadIdx.x;
  r1[t] = lq1[t] * lk1[t];
  r2[t] = lq2[t] * lk2[t];
  __syncthreads();
  for (int s = 64; s > 0; s >>= 1) {
    if (t < s) { r1[t] += r1[t + s]; r2[t] += r2[t + s]; }
    __syncthreads();
  }
  if (t == 0) *lbd = expf(r1[0]) - expf(r2[0]) + 0.8f;
}

// --------------------------- pack W: lane-contiguous B-frag chunks ----------
// Wp chunk (ntile 0..39, ks 0..31): 1KB = 64 lanes x 16B; lane (quad,l15):
//   n = ntile*16 + l15, k = ks*32 + quad*8 .. +7.  ntile: q 0-15, k 16-31, v 32-39.
__global__ __launch_bounds__(256) void pack_w(
    const float* __restrict__ Wq, const float* __restrict__ Wk,
    const float* __restrict__ Wv, __bf16* __restrict__ Wp) {
  int nt = blockIdx.x;  // 0..39
  const float* W; int colbase, N;
  if (nt < 16)      { W = Wq; colbase = nt * 16;        N = 256; }
  else if (nt < 32) { W = Wk; colbase = (nt - 16) * 16; N = 256; }
  else              { W = Wv; colbase = (nt - 32) * 16; N = 128; }
  int tid = threadIdx.x;
#pragma unroll
  for (int i = 0; i < 8; ++i) {
    int u = tid + 256 * i;            // 2048 = 32 ks * 64 lanes
    int ks = u >> 6, lane = u & 63;
    int l15 = lane & 15, quad = lane >> 4;
    bf16x8 pk;
#pragma unroll
    for (int j = 0; j < 8; ++j)
      pk[j] = (__bf16)W[(size_t)(ks * 32 + quad * 8 + j) * N + colbase + l15];
    *(bf16x8*)(Wp + ((size_t)(nt * 32 + ks) * 64 + lane) * 8) = pk;
  }
}

// --------------------------- projection GEMM body (templated on NT) ---------
// NT = n-tiles of 16 (16 for q/k, 8 for v); NTG = n-tile offset into Wp.
// Block = 128 rows x all N. BK=32 double-buffered global_load_lds staging.
template<int NT, int NTG>
__device__ __forceinline__ void proj_body(
    const float* __restrict__ Ablk, const __bf16* __restrict__ Wp,
    __bf16* __restrict__ outp, __bf16* __restrict__ Vt,
    int rows0, char* smem) {
  float*  sA = (float*)smem;                    // 2 x 4096 floats (32KB)
  __bf16* sB = (__bf16*)(smem + 32768);         // 2 x 8192 bf16  (32KB)
  const int tid = threadIdx.x;
  const int lane = tid & 63, wave = tid >> 6;
  const int l15 = lane & 15, quad = lane >> 4;
  const int arow = lane >> 3;                   // A-staging row-within-8
  const int ac16 = (lane & 7) ^ arow;           // XOR swizzle (row&7)

  f32x4 acc0[NT], acc1[NT];
#pragma unroll
  for (int j = 0; j < NT; ++j) {
    acc0[j] = (f32x4){0.f, 0.f, 0.f, 0.f};
    acc1[j] = (f32x4){0.f, 0.f, 0.f, 0.f};
  }

  auto stage_ks = [&](int ks, int buf) {
    const float* gA = Ablk + ks * 32;
    float* lA = sA + buf * 4096;
#pragma unroll
    for (int i = 0; i < 4; ++i) {
      int li = wave * 4 + i;                     // 16 loads, 8 rows each
      gld16(gA + (size_t)(li * 8 + arow) * CDIM + ac16 * 4, lA + li * 256);
    }
    __bf16* lB = sB + buf * 8192;
#pragma unroll
    for (int i = 0; i < 4; ++i) {
      int ntl = wave * 4 + i;                    // one 1KB chunk per n-tile
      if (ntl < NT)
        gld16(Wp + ((size_t)((NTG + ntl) * 32 + ks) * 64 + lane) * 8,
              lB + ntl * 512);
    }
  };

  stage_ks(0, 0);
  for (int ks = 0; ks < 32; ++ks) {
    const int buf = ks & 1;
    __syncthreads();
    // A frags (un-swizzle: chunk c of row r lives at LDS pos c^(r&7))
    const float* lA = sA + buf * 4096;
    int r0 = wave * 32 + l15;
    f32x4 lo0 = *(const f32x4*)(lA + r0 * 32 + (((quad * 2)     ^ (l15 & 7)) * 4));
    f32x4 hi0 = *(const f32x4*)(lA + r0 * 32 + (((quad * 2 + 1) ^ (l15 & 7)) * 4));
    bf16x8 af0 = cvt8(lo0, hi0);
    int r1 = r0 + 16;
    f32x4 lo1 = *(const f32x4*)(lA + r1 * 32 + (((quad * 2)     ^ (l15 & 7)) * 4));
    f32x4 hi1 = *(const f32x4*)(lA + r1 * 32 + (((quad * 2 + 1) ^ (l15 & 7)) * 4));
    bf16x8 af1 = cvt8(lo1, hi1);
    if (ks < 31) stage_ks(ks + 1, buf ^ 1);      // prefetch overlaps MFMA
    const __bf16* lB = sB + buf * 8192;
#pragma unroll
    for (int nt = 0; nt < NT; ++nt) {            // constexpr trip count!
      bf16x8 bf = *(const bf16x8*)(lB + nt * 512 + lane * 8);
      acc0[nt] = MFMA16(af0, bf, acc0[nt], 0, 0, 0);
      acc1[nt] = MFMA16(af1, bf, acc1[nt], 0, 0, 0);
    }
  }

  // ---- epilogue: C through LDS tile -> coalesced 16B stores ----
  __syncthreads();
  __bf16* tile = (__bf16*)smem;                  // [128][136] bf16 (34.8KB)
  constexpr int N = NT * 16;
#pragma unroll
  for (int half = 0; half < (NT >> 3); ++half) {
#pragma unroll
    for (int ntl = 0; ntl < 8; ++ntl) {
      f32x4 a0 = acc0[half * 8 + ntl];
      f32x4 a1 = acc1[half * 8 + ntl];
#pragma unroll
      for (int r = 0; r < 4; ++r) {
        tile[(wave * 32 + quad * 4 + r) * 136 + ntl * 16 + l15] = (__bf16)a0[r];
        tile[(wave * 32 + 16 + quad * 4 + r) * 136 + ntl * 16 + l15] = (__bf16)a1[r];
      }
    }
    __syncthreads();
#pragma unroll
    for (int i = 0; i < 8; ++i) {
      int u = tid + 256 * i;                     // 2048 chunks: 128 rows x 16x16B
      int row = u >> 4, c8 = u & 15;
      bf16x8 val = *(const bf16x8*)(tile + row * 136 + c8 * 8);
      *(bf16x8*)(outp + (size_t)(rows0 + row) * N + half * 128 + c8 * 8) = val;
    }
    if constexpr (NT == 8) {                     // v: also Vt[b][c][t] via transpose
      int b = rows0 >> 11, t0 = rows0 & 2047;
#pragma unroll
      for (int i = 0; i < 8; ++i) {
        int u = tid + 256 * i;                   // 2048 = 16 tc x 128 c
        int tc = u & 15, c = u >> 4;
        bf16x8 pk;
#pragma unroll
        for (int j = 0; j < 8; ++j) pk[j] = tile[(tc * 8 + j) * 136 + c];
        *(bf16x8*)(Vt + ((size_t)(b * 128 + c)) * T_SEQ + t0 + tc * 8) = pk;
      }
    }
    __syncthreads();
  }
}

// 384 blocks x 256 thr. Blocks 0..127: q->Q(N=256); 128..255: k->K; 256..383: v->V(+Vt).
__global__ __launch_bounds__(256, 2) void proj_mfma(
    const float* __restrict__ qin, const float* __restrict__ kin,
    const float* __restrict__ vin, const __bf16* __restrict__ Wp,
    __bf16* __restrict__ Qo, __bf16* __restrict__ Ko,
    __bf16* __restrict__ Vo, __bf16* __restrict__ Vt) {
  __shared__ char smem[65536];
  const int blk = blockIdx.x;
  const int rows0 = (blk & 127) * 128;
  if (blk < 128)
    proj_body<16, 0>(qin + (size_t)rows0 * CDIM, Wp, Qo, nullptr, rows0, smem);
  else if (blk < 256)
    proj_body<16, 16>(kin + (size_t)rows0 * CDIM, Wp, Ko, nullptr, rows0, smem);
  else
    proj_body<8, 32>(vin + (size_t)rows0 * CDIM, Wp, Vo, Vt, rows0, smem);
}

// --------------------------- V prefix sums (bf16 in, fp32 out) --------------
__global__ __launch_bounds__(128) void vcsum_a(const __bf16* __restrict__ V,
                                               float* __restrict__ csum) {
  int blk = blockIdx.x; int b = blk >> 4, ch = blk & 15;
  int c = threadIdx.x;
  const __bf16* vp = V + ((size_t)b * T_SEQ + ch * 128) * HS + c;
  float s = 0.f;
#pragma unroll 4
  for (int t = 0; t < 128; ++t) s += (float)vp[(size_t)t * HS];
  csum[(size_t)blk * HS + c] = s;
}

__global__ __launch_bounds__(128) void vcsum_b(const __bf16* __restrict__ V,
                                               const float* __restrict__ csum,
                                               float* __restrict__ cum) {
  int blk = blockIdx.x; int b = blk >> 4, ch = blk & 15;
  int c = threadIdx.x;
  float run = 0.f;
  for (int j = 0; j < ch; ++j) run += csum[(size_t)(b * 16 + j) * HS + c];
  const __bf16* vp = V + ((size_t)b * T_SEQ + ch * 128) * HS + c;
  float* cp = cum + ((size_t)b * (T_SEQ + 1) + ch * 128) * HS + c;
  if (ch == 0) cp[0] = 0.f;
#pragma unroll 4
  for (int t = 0; t < 128; ++t) {
    run += (float)vp[(size_t)t * HS];
    cp[(size_t)(t + 1) * HS] = run;
  }
}

// --------------------------- attention (bf16 MFMA, flash-style) -------------
// 256 blocks x 1024 thr (16 waves: wm = wave>>3 m-split, wk = wave&7 key-split).
// BK=256 per iteration. Block p: batch b = p&7 (XCD locality), pair pr = p>>3;
// phases ti = pr, 63-pr (triangle pairing -> ~10 BK=256 k-iters per block).
// amdgpu_waves_per_eu(4,4): pin occupancy target to the LDS-limited 16
// waves/CU so the allocator gets the full 128-VGPR budget (r7/r8: backend
// targeted 8 waves/EU -> 64 VGPR -> 49MB scratch spill).
__global__ __launch_bounds__(1024) __attribute__((amdgpu_waves_per_eu(4, 4)))
void attn_mfma(
    const __bf16* __restrict__ Q, const __bf16* __restrict__ K,
    const __bf16* __restrict__ Vt, const float* __restrict__ cum,
    const int* __restrict__ pad, const float* __restrict__ lbdp,
    float* __restrict__ out) {
  __shared__ __bf16 sQ[32 * 264];            // 32 rows x 256, stride 264 (pad)
  __shared__ __bf16 sP[2][2][32 * 264];      // [buf][mat][row*264+key], pad 8
  __shared__ float zb[2][32][128];
  __shared__ float zfin[2][32];

  const int tid = threadIdx.x;
  const int lane = tid & 63, wave = tid >> 6;   // 16 waves
  const int wm = wave >> 3, wk = wave & 7;      // wm: rows 2x16, wk: keys 8x32
  const int l15 = lane & 15, quad = lane >> 4;

  const int p = blockIdx.x;
  const int b = p & 7, pr = p >> 3;
  const float lbd = *lbdp;
  const __bf16* Qb = Q + (size_t)b * T_SEQ * 256;
  const __bf16* Kb = K + (size_t)b * T_SEQ * 256;
  const __bf16* Vtb = Vt + (size_t)b * HS * T_SEQ;
  const float* cumb = cum + (size_t)b * (T_SEQ + 1) * HS;
  const float pc = (1.f - lbd) * (1.f / (float)T_SEQ);

  for (int ph = 0; ph < 2; ++ph) {
    const int ti = ph ? (63 - pr) : pr;
    const int q0 = ti * 32;

    // ---- stage Q tile (16KB): 1024 16B-chunks, one per thread ----
    {
      int row = tid >> 5, c16 = tid & 31;
      *(f32x4*)(&sQ[row * 264 + c16 * 8]) =
          *(const f32x4*)(Qb + (size_t)(q0 + row) * 256 + c16 * 8);
    }
    __syncthreads();

    // ---- preload Q A-frags (rows wm*16+l15, both planes, 4 ksteps) ----
    bf16x8 qf[2][4];
    {
      const int row = wm * 16 + l15;
#pragma unroll
      for (int pl = 0; pl < 2; ++pl)
#pragma unroll
        for (int s = 0; s < 4; ++s)
          qf[pl][s] = *(const bf16x8*)(&sQ[row * 264 + pl * 128 + s * 32 + quad * 8]);
    }

    f32x4 O[2];
    O[0] = (f32x4){0.f, 0.f, 0.f, 0.f};
    O[1] = (f32x4){0.f, 0.f, 0.f, 0.f};
    float z[2][4] = {};

    const int lastkey = q0 + 32;             // max allowed key (row q0+31, +1 lookahead)
    const int nkt = (min(lastkey, T_SEQ - 1) >> 8) + 1;

    for (int kt = 0; kt < nkt; ++kt) {
      const int k0 = kt << 8;
      const bool needmask = (k0 + 255 > q0 + 1);
      const int buf = kt & 1;

#pragma unroll
      for (int mat = 0; mat < 2; ++mat) {
        // K B-frags direct from global (L2): keys k0+wk*32+{0,16}+l15
        const __bf16* kp = Kb + (size_t)(k0 + wk * 32 + l15) * 256 + mat * 128 + quad * 8;
        bf16x8 ka0 = *(const bf16x8*)(kp);
        bf16x8 ka1 = *(const bf16x8*)(kp + 32);
        bf16x8 ka2 = *(const bf16x8*)(kp + 64);
        bf16x8 ka3 = *(const bf16x8*)(kp + 96);
        const __bf16* kq = kp + 16 * 256;
        bf16x8 kb0 = *(const bf16x8*)(kq);
        bf16x8 kb1 = *(const bf16x8*)(kq + 32);
        bf16x8 kb2 = *(const bf16x8*)(kq + 64);
        bf16x8 kb3 = *(const bf16x8*)(kq + 96);
        f32x4 S0 = (f32x4){0.f, 0.f, 0.f, 0.f}, S1 = S0;
        S0 = MFMA16(qf[mat][0], ka0, S0, 0, 0, 0);
        S0 = MFMA16(qf[mat][1], ka1, S0, 0, 0, 0);
        S0 = MFMA16(qf[mat][2], ka2, S0, 0, 0, 0);
        S0 = MFMA16(qf[mat][3], ka3, S0, 0, 0, 0);
        S1 = MFMA16(qf[mat][0], kb0, S1, 0, 0, 0);
        S1 = MFMA16(qf[mat][1], kb1, S1, 0, 0, 0);
        S1 = MFMA16(qf[mat][2], kb2, S1, 0, 0, 0);
        S1 = MFMA16(qf[mat][3], kb3, S1, 0, 0, 0);

        // exp + z partials + write P (bf16) to LDS
        const int rowl = wm * 16 + quad * 4;
#pragma unroll
        for (int nt = 0; nt < 2; ++nt) {
          const int keyg = k0 + wk * 32 + nt * 16 + l15;
          const f32x4 Sv = nt ? S1 : S0;
#pragma unroll
          for (int r = 0; r < 4; ++r) {
            float pv;
            if (needmask) {
              int rowg = q0 + rowl + r;
              pv = (keyg <= rowg + 1) ? __expf(Sv[r] * SCALE) : 0.f;
            } else {
              pv = __expf(Sv[r] * SCALE);
            }
            z[mat][r] += pv;
            sP[buf][mat][(rowl + r) * 264 + wk * 32 + nt * 16 + l15] = (__bf16)pv;
          }
        }
      }
      __syncthreads();

      // PV: O += P @ V  (P A-frags from LDS; V B-frags direct from global Vt)
      // each wave: 16 output cols (wk*16+l15), all 256 keys of the tile
#pragma unroll
      for (int ks = 0; ks < 8; ++ks) {
        bf16x8 pf0 = *(const bf16x8*)(&sP[buf][0][(wm * 16 + l15) * 264 + ks * 32 + quad * 8]);
        bf16x8 pf1 = *(const bf16x8*)(&sP[buf][1][(wm * 16 + l15) * 264 + ks * 32 + quad * 8]);
        bf16x8 vf = *(const bf16x8*)(Vtb + (size_t)(wk * 16 + l15) * T_SEQ +
                                     k0 + ks * 32 + quad * 8);
        O[0] = MFMA16(pf0, vf, O[0], 0, 0, 0);
        O[1] = MFMA16(pf1, vf, O[1], 0, 0, 0);
      }
      // no trailing barrier: sP is double-buffered
    }

    // ---- Z reduction ----
#pragma unroll
    for (int mat = 0; mat < 2; ++mat)
#pragma unroll
      for (int r = 0; r < 4; ++r)
        zb[mat][wm * 16 + quad * 4 + r][wk * 16 + l15] = z[mat][r];
    __syncthreads();
    if (tid < 64) {
      int mat = tid >> 5, row = tid & 31;
      float s = 0.f;
#pragma unroll
      for (int j = 0; j < 128; ++j) s += zb[mat][row][(j + tid) & 127];  // bank-spread
      zfin[mat][row] = s;
    }
    __syncthreads();

    // ---- epilogue: normalize + closed-form masked tail + pad rows ----
    {
      const int col = wk * 16 + l15;
      const float ct = cumb[(size_t)T_SEQ * HS + col];
#pragma unroll
      for (int r = 0; r < 4; ++r) {
        const int rowl = wm * 16 + quad * 4 + r;
        const int rowg = q0 + rowl;
        const int nallow = min(rowg + 2, T_SEQ);
        const float nmask = (float)(T_SEQ - nallow);
        const float Z1 = zfin[0][rowl] + nmask;
        const float Z2 = zfin[1][rowl] + nmask;
        const float i1 = 1.f / Z1, i2 = lbd / Z2;
        const float tc = i1 - i2;
        const bool isp = (pad[b * T_SEQ + rowg] == 1);
        const float cn = cumb[(size_t)nallow * HS + col];
        float val = isp ? (pc * ct)
                        : (O[0][r] * i1 - O[1][r] * i2 + tc * (ct - cn));
        out[((size_t)b * T_SEQ + rowg) * HS + col] = val;
      }
    }
    __syncthreads();   // before next phase restages sQ
  }
}

// ---------------------------------------------------------------------------
extern "C" void kernel_launch(void* const* d_in, const int* in_sizes, int n_in,
                              void* d_out, int out_size, void* d_ws, size_t ws_size,
                              hipStream_t stream) {
  (void)in_sizes; (void)n_in; (void)out_size; (void)ws_size;
  const float* q   = (const float*)d_in[0];
  const float* k   = (const float*)d_in[1];
  const float* v   = (const float*)d_in[2];
  const int*   pm  = (const int*)d_in[3];
  const float* Wq  = (const float*)d_in[4];
  const float* Wk  = (const float*)d_in[5];
  const float* Wv  = (const float*)d_in[6];
  const float* lq1 = (const float*)d_in[7];
  const float* lk1 = (const float*)d_in[8];
  const float* lq2 = (const float*)d_in[9];
  const float* lk2 = (const float*)d_in[10];
  float* out = (float*)d_out;
  char* ws = (char*)d_ws;

  // workspace layout (bytes)
  float*  lbd  = (float*)ws;                                   // 16
  __bf16* Wp   = (__bf16*)(ws + 16);                           // 40*32*64*8*2 = 1310720
  __bf16* Qp   = (__bf16*)(ws + 16 + 1310720);                 // 8*2048*256*2
  __bf16* Kp   = Qp + (size_t)NB * T_SEQ * 256;
  __bf16* Vp   = Kp + (size_t)NB * T_SEQ * 256;                // 8*2048*128*2
  __bf16* Vt   = Vp + (size_t)NB * T_SEQ * HS;
  float*  cum  = (float*)(Vt + (size_t)NB * T_SEQ * HS);       // 8*2049*128*4
  float*  csum = cum + (size_t)NB * (T_SEQ + 1) * HS;          // 8*16*128*4

  lambda_kernel<<<dim3(1), dim3(128), 0, stream>>>(lq1, lk1, lq2, lk2, lbd);
  pack_w<<<dim3(40), dim3(256), 0, stream>>>(Wq, Wk, Wv, Wp);
  proj_mfma<<<dim3(384), dim3(256), 0, stream>>>(q, k, v, Wp, Qp, Kp, Vp, Vt);
  vcsum_a<<<dim3(128), dim3(128), 0, stream>>>(Vp, csum);
  vcsum_b<<<dim3(128), dim3(128), 0, stream>>>(Vp, csum, cum);
  attn_mfma<<<dim3(256), dim3(1024), 0, stream>>>(Qp, Kp, Vt, cum, pm, lbd, out);
}

// Round 4
// 379.409 us; speedup vs baseline: 1.0489x; 1.0489x over previous
//
#include <hip/hip_runtime.h>
#include <math.h>

// ---------------------------------------------------------------------------
// DiffHead, MFMA edition, round 10: revert to the r6 512-thread attn shape
//   (122us, VGPR=100, no spill) and fix its real limiter: grid=256 on 256 CUs
//   meant 1 block/CU, so the barrier-paced per-iteration latency chain
//   (K-frag L2 loads -> MFMA -> exp -> barrier -> PV) had nothing to overlap
//   with (Occupancy 21.7%). LDS 68.6KB and VGPR 100 allow 2 blocks/CU; only
//   the grid prevented it. r7-r9's 1024-thread attempt is abandoned: the
//   backend pins that shape at 64 VGPR -> 49MB scratch spill regardless of
//   launch_bounds / amdgpu_waves_per_eu.
//   Change: 512 blocks, one 32-row q-tile each; ti = q<32 ? q : 95-q pairs
//   long+short tiles on (likely co-resident) blocks p and p+256. Two
//   independent blocks per CU overlap each other's stalls (no shared barrier).
// Math identical: fill=1e-9 => exp(fill*scale)==1.0f -> masked tail
//   closed-form via V prefix sums; padded rows closed form; fixed shift m=0.
// MFMA 16x16x32_bf16 layouts: A/B lane: m/n=lane&15, k=quad*8+j (16B contig);
//   C/D: col=lane&15, row=quad*4+reg.
// ---------------------------------------------------------------------------

#define T_SEQ 2048
#define NB 8
#define CDIM 1024
#define HS 128

constexpr float SCALE = 0.08838834764831845f;   // 128^-0.5

typedef float f32x4 __attribute__((ext_vector_type(4)));
typedef __bf16 bf16x8 __attribute__((ext_vector_type(8)));
typedef unsigned int u32;

#define MFMA16 __builtin_amdgcn_mfma_f32_16x16x32_bf16

__device__ __forceinline__ void gld16(const void* g, void* l) {
  __builtin_amdgcn_global_load_lds(
      (const __attribute__((address_space(1))) u32*)g,
      (__attribute__((address_space(3))) u32*)l, 16, 0, 0);
}

__device__ __forceinline__ bf16x8 cvt8(f32x4 lo, f32x4 hi) {
  bf16x8 r;
  r[0] = (__bf16)lo.x; r[1] = (__bf16)lo.y; r[2] = (__bf16)lo.z; r[3] = (__bf16)lo.w;
  r[4] = (__bf16)hi.x; r[5] = (__bf16)hi.y; r[6] = (__bf16)hi.z; r[7] = (__bf16)hi.w;
  return r;
}

// --------------------------- lambda = exp(lq1.lk1) - exp(lq2.lk2) + 0.8 -----
__global__ __launch_bounds__(128) void lambda_kernel(
    const float* __restrict__ lq1, const float* __restrict__ lk1,
    const float* __restrict__ lq2, const float* __restrict__ lk2,
    float* __restrict__ lbd) {
  __shared__ float r1[128], r2[128];
  int t = threadIdx.x;
  r1[t] = lq1[t] * lk1[t];
  r2[t] = lq2[t] * lk2[t];
  __syncthreads();
  for (int s = 64; s > 0; s >>= 1) {
    if (t < s) { r1[t] += r1[t + s]; r2[t] += r2[t + s]; }
    __syncthreads();
  }
  if (t == 0) *lbd = expf(r1[0]) - expf(r2[0]) + 0.8f;
}

// --------------------------- pack W: lane-contiguous B-frag chunks ----------
// Wp chunk (ntile 0..39, ks 0..31): 1KB = 64 lanes x 16B; lane (quad,l15):
//   n = ntile*16 + l15, k = ks*32 + quad*8 .. +7.  ntile: q 0-15, k 16-31, v 32-39.
__global__ __launch_bounds__(256) void pack_w(
    const float* __restrict__ Wq, const float* __restrict__ Wk,
    const float* __restrict__ Wv, __bf16* __restrict__ Wp) {
  int nt = blockIdx.x;  // 0..39
  const float* W; int colbase, N;
  if (nt < 16)      { W = Wq; colbase = nt * 16;        N = 256; }
  else if (nt < 32) { W = Wk; colbase = (nt - 16) * 16; N = 256; }
  else              { W = Wv; colbase = (nt - 32) * 16; N = 128; }
  int tid = threadIdx.x;
#pragma unroll
  for (int i = 0; i < 8; ++i) {
    int u = tid + 256 * i;            // 2048 = 32 ks * 64 lanes
    int ks = u >> 6, lane = u & 63;
    int l15 = lane & 15, quad = lane >> 4;
    bf16x8 pk;
#pragma unroll
    for (int j = 0; j < 8; ++j)
      pk[j] = (__bf16)W[(size_t)(ks * 32 + quad * 8 + j) * N + colbase + l15];
    *(bf16x8*)(Wp + ((size_t)(nt * 32 + ks) * 64 + lane) * 8) = pk;
  }
}

// --------------------------- projection GEMM body (templated on NT) ---------
// NT = n-tiles of 16 (16 for q/k, 8 for v); NTG = n-tile offset into Wp.
// Block = 128 rows x all N. BK=32 double-buffered global_load_lds staging.
template<int NT, int NTG>
__device__ __forceinline__ void proj_body(
    const float* __restrict__ Ablk, const __bf16* __restrict__ Wp,
    __bf16* __restrict__ outp, __bf16* __restrict__ Vt,
    int rows0, char* smem) {
  float*  sA = (float*)smem;                    // 2 x 4096 floats (32KB)
  __bf16* sB = (__bf16*)(smem + 32768);         // 2 x 8192 bf16  (32KB)
  const int tid = threadIdx.x;
  const int lane = tid & 63, wave = tid >> 6;
  const int l15 = lane & 15, quad = lane >> 4;
  const int arow = lane >> 3;                   // A-staging row-within-8
  const int ac16 = (lane & 7) ^ arow;           // XOR swizzle (row&7)

  f32x4 acc0[NT], acc1[NT];
#pragma unroll
  for (int j = 0; j < NT; ++j) {
    acc0[j] = (f32x4){0.f, 0.f, 0.f, 0.f};
    acc1[j] = (f32x4){0.f, 0.f, 0.f, 0.f};
  }

  auto stage_ks = [&](int ks, int buf) {
    const float* gA = Ablk + ks * 32;
    float* lA = sA + buf * 4096;
#pragma unroll
    for (int i = 0; i < 4; ++i) {
      int li = wave * 4 + i;                     // 16 loads, 8 rows each
      gld16(gA + (size_t)(li * 8 + arow) * CDIM + ac16 * 4, lA + li * 256);
    }
    __bf16* lB = sB + buf * 8192;
#pragma unroll
    for (int i = 0; i < 4; ++i) {
      int ntl = wave * 4 + i;                    // one 1KB chunk per n-tile
      if (ntl < NT)
        gld16(Wp + ((size_t)((NTG + ntl) * 32 + ks) * 64 + lane) * 8,
              lB + ntl * 512);
    }
  };

  stage_ks(0, 0);
  for (int ks = 0; ks < 32; ++ks) {
    const int buf = ks & 1;
    __syncthreads();
    // A frags (un-swizzle: chunk c of row r lives at LDS pos c^(r&7))
    const float* lA = sA + buf * 4096;
    int r0 = wave * 32 + l15;
    f32x4 lo0 = *(const f32x4*)(lA + r0 * 32 + (((quad * 2)     ^ (l15 & 7)) * 4));
    f32x4 hi0 = *(const f32x4*)(lA + r0 * 32 + (((quad * 2 + 1) ^ (l15 & 7)) * 4));
    bf16x8 af0 = cvt8(lo0, hi0);
    int r1 = r0 + 16;
    f32x4 lo1 = *(const f32x4*)(lA + r1 * 32 + (((quad * 2)     ^ (l15 & 7)) * 4));
    f32x4 hi1 = *(const f32x4*)(lA + r1 * 32 + (((quad * 2 + 1) ^ (l15 & 7)) * 4));
    bf16x8 af1 = cvt8(lo1, hi1);
    if (ks < 31) stage_ks(ks + 1, buf ^ 1);      // prefetch overlaps MFMA
    const __bf16* lB = sB + buf * 8192;
#pragma unroll
    for (int nt = 0; nt < NT; ++nt) {            // constexpr trip count!
      bf16x8 bf = *(const bf16x8*)(lB + nt * 512 + lane * 8);
      acc0[nt] = MFMA16(af0, bf, acc0[nt], 0, 0, 0);
      acc1[nt] = MFMA16(af1, bf, acc1[nt], 0, 0, 0);
    }
  }

  // ---- epilogue: C through LDS tile -> coalesced 16B stores ----
  __syncthreads();
  __bf16* tile = (__bf16*)smem;                  // [128][136] bf16 (34.8KB)
  constexpr int N = NT * 16;
#pragma unroll
  for (int half = 0; half < (NT >> 3); ++half) {
#pragma unroll
    for (int ntl = 0; ntl < 8; ++ntl) {
      f32x4 a0 = acc0[half * 8 + ntl];
      f32x4 a1 = acc1[half * 8 + ntl];
#pragma unroll
      for (int r = 0; r < 4; ++r) {
        tile[(wave * 32 + quad * 4 + r) * 136 + ntl * 16 + l15] = (__bf16)a0[r];
        tile[(wave * 32 + 16 + quad * 4 + r) * 136 + ntl * 16 + l15] = (__bf16)a1[r];
      }
    }
    __syncthreads();
#pragma unroll
    for (int i = 0; i < 8; ++i) {
      int u = tid + 256 * i;                     // 2048 chunks: 128 rows x 16x16B
      int row = u >> 4, c8 = u & 15;
      bf16x8 val = *(const bf16x8*)(tile + row * 136 + c8 * 8);
      *(bf16x8*)(outp + (size_t)(rows0 + row) * N + half * 128 + c8 * 8) = val;
    }
    if constexpr (NT == 8) {                     // v: also Vt[b][c][t] via transpose
      int b = rows0 >> 11, t0 = rows0 & 2047;
#pragma unroll
      for (int i = 0; i < 8; ++i) {
        int u = tid + 256 * i;                   // 2048 = 16 tc x 128 c
        int tc = u & 15, c = u >> 4;
        bf16x8 pk;
#pragma unroll
        for (int j = 0; j < 8; ++j) pk[j] = tile[(tc * 8 + j) * 136 + c];
        *(bf16x8*)(Vt + ((size_t)(b * 128 + c)) * T_SEQ + t0 + tc * 8) = pk;
      }
    }
    __syncthreads();
  }
}

// 384 blocks x 256 thr. Blocks 0..127: q->Q(N=256); 128..255: k->K; 256..383: v->V(+Vt).
__global__ __launch_bounds__(256, 2) void proj_mfma(
    const float* __restrict__ qin, const float* __restrict__ kin,
    const float* __restrict__ vin, const __bf16* __restrict__ Wp,
    __bf16* __restrict__ Qo, __bf16* __restrict__ Ko,
    __bf16* __restrict__ Vo, __bf16* __restrict__ Vt) {
  __shared__ char smem[65536];
  const int blk = blockIdx.x;
  const int rows0 = (blk & 127) * 128;
  if (blk < 128)
    proj_body<16, 0>(qin + (size_t)rows0 * CDIM, Wp, Qo, nullptr, rows0, smem);
  else if (blk < 256)
    proj_body<16, 16>(kin + (size_t)rows0 * CDIM, Wp, Ko, nullptr, rows0, smem);
  else
    proj_body<8, 32>(vin + (size_t)rows0 * CDIM, Wp, Vo, Vt, rows0, smem);
}

// --------------------------- V prefix sums (bf16 in, fp32 out) --------------
__global__ __launch_bounds__(128) void vcsum_a(const __bf16* __restrict__ V,
                                               float* __restrict__ csum) {
  int blk = blockIdx.x; int b = blk >> 4, ch = blk & 15;
  int c = threadIdx.x;
  const __bf16* vp = V + ((size_t)b * T_SEQ + ch * 128) * HS + c;
  float s = 0.f;
#pragma unroll 4
  for (int t = 0; t < 128; ++t) s += (float)vp[(size_t)t * HS];
  csum[(size_t)blk * HS + c] = s;
}

__global__ __launch_bounds__(128) void vcsum_b(const __bf16* __restrict__ V,
                                               const float* __restrict__ csum,
                                               float* __restrict__ cum) {
  int blk = blockIdx.x; int b = blk >> 4, ch = blk & 15;
  int c = threadIdx.x;
  float run = 0.f;
  for (int j = 0; j < ch; ++j) run += csum[(size_t)(b * 16 + j) * HS + c];
  const __bf16* vp = V + ((size_t)b * T_SEQ + ch * 128) * HS + c;
  float* cp = cum + ((size_t)b * (T_SEQ + 1) + ch * 128) * HS + c;
  if (ch == 0) cp[0] = 0.f;
#pragma unroll 4
  for (int t = 0; t < 128; ++t) {
    run += (float)vp[(size_t)t * HS];
    cp[(size_t)(t + 1) * HS] = run;
  }
}

// --------------------------- attention (bf16 MFMA, flash-style) -------------
// 512 blocks x 512 thr (8 waves: wm = wave>>2 m-split, wk = wave&3 key-split).
// One 32-row q-tile per block. Block p: b = p&7, q = p>>3 in [0,64);
//   ti = q<32 ? q : 95-q  -> blocks p and p+256 (likely co-resident) get
//   tiles ti and 63-ti: per-CU work ~constant, and the two independent
//   blocks overlap each other's load/barrier stalls (2 blocks/CU now fits:
//   LDS 68.6KB*2 < 160KB, VGPR 100 -> 5 waves/EU >= 4 needed).
__global__ __launch_bounds__(512, 2) void attn_mfma(
    const __bf16* __restrict__ Q, const __bf16* __restrict__ K,
    const __bf16* __restrict__ Vt, const float* __restrict__ cum,
    const int* __restrict__ pad, const float* __restrict__ lbdp,
    float* __restrict__ out) {
  __shared__ __bf16 sQ[32 * 264];            // 32 rows x 256, stride 264 (pad)
  __shared__ __bf16 sP[2][2][32 * 136];      // [buf][mat][row*136+key], pad 8
  __shared__ float zb[2][32][64];
  __shared__ float zfin[2][32];

  const int tid = threadIdx.x;
  const int lane = tid & 63, wave = tid >> 6;
  const int wm = wave >> 2, wk = wave & 3;
  const int l15 = lane & 15, quad = lane >> 4;

  const int p = blockIdx.x;
  const int b = p & 7, q = p >> 3;
  const int ti = (q < 32) ? q : (95 - q);
  const int q0 = ti * 32;
  const float lbd = *lbdp;
  const __bf16* Qb = Q + (size_t)b * T_SEQ * 256;
  const __bf16* Kb = K + (size_t)b * T_SEQ * 256;
  const __bf16* Vtb = Vt + (size_t)b * HS * T_SEQ;
  const float* cumb = cum + (size_t)b * (T_SEQ + 1) * HS;
  const float pc = (1.f - lbd) * (1.f / (float)T_SEQ);

  // ---- stage Q tile (16KB) ----
#pragma unroll
  for (int i = 0; i < 2; ++i) {
    int c = tid + 512 * i;                 // 1024 16B-chunks
    int row = c >> 5, c16 = c & 31;
    *(f32x4*)(&sQ[row * 264 + c16 * 8]) =
        *(const f32x4*)(Qb + (size_t)(q0 + row) * 256 + c16 * 8);
  }
  __syncthreads();

  // ---- preload Q A-frags (rows wm*16+l15, both planes, 4 ksteps) ----
  bf16x8 qf[2][4];
  {
    const int row = wm * 16 + l15;
#pragma unroll
    for (int pl = 0; pl < 2; ++pl)
#pragma unroll
      for (int s = 0; s < 4; ++s)
        qf[pl][s] = *(const bf16x8*)(&sQ[row * 264 + pl * 128 + s * 32 + quad * 8]);
  }

  f32x4 O[2][2];
#pragma unroll
  for (int i = 0; i < 2; ++i)
#pragma unroll
    for (int j = 0; j < 2; ++j) O[i][j] = (f32x4){0.f, 0.f, 0.f, 0.f};
  float z[2][4] = {};

  const int lastkey = q0 + 32;             // max allowed key (row q0+31, +1 lookahead)
  const int nkt = (min(lastkey, T_SEQ - 1) >> 7) + 1;

  for (int kt = 0; kt < nkt; ++kt) {
    const int k0 = kt << 7;
    const bool needmask = (k0 + 127 > q0 + 1);
    const int buf = kt & 1;

#pragma unroll
    for (int mat = 0; mat < 2; ++mat) {
      // K B-frags direct from global (L2): keys k0+wk*32+{0,16}+l15
      const __bf16* kp = Kb + (size_t)(k0 + wk * 32 + l15) * 256 + mat * 128 + quad * 8;
      bf16x8 ka0 = *(const bf16x8*)(kp);
      bf16x8 ka1 = *(const bf16x8*)(kp + 32);
      bf16x8 ka2 = *(const bf16x8*)(kp + 64);
      bf16x8 ka3 = *(const bf16x8*)(kp + 96);
      const __bf16* kq = kp + 16 * 256;
      bf16x8 kb0 = *(const bf16x8*)(kq);
      bf16x8 kb1 = *(const bf16x8*)(kq + 32);
      bf16x8 kb2 = *(const bf16x8*)(kq + 64);
      bf16x8 kb3 = *(const bf16x8*)(kq + 96);
      f32x4 S0 = (f32x4){0.f, 0.f, 0.f, 0.f}, S1 = S0;
      S0 = MFMA16(qf[mat][0], ka0, S0, 0, 0, 0);
      S0 = MFMA16(qf[mat][1], ka1, S0, 0, 0, 0);
      S0 = MFMA16(qf[mat][2], ka2, S0, 0, 0, 0);
      S0 = MFMA16(qf[mat][3], ka3, S0, 0, 0, 0);
      S1 = MFMA16(qf[mat][0], kb0, S1, 0, 0, 0);
      S1 = MFMA16(qf[mat][1], kb1, S1, 0, 0, 0);
      S1 = MFMA16(qf[mat][2], kb2, S1, 0, 0, 0);
      S1 = MFMA16(qf[mat][3], kb3, S1, 0, 0, 0);

      // exp + z partials + write P (bf16) to LDS
      const int rowl = wm * 16 + quad * 4;
#pragma unroll
      for (int nt = 0; nt < 2; ++nt) {
        const int keyg = k0 + wk * 32 + nt * 16 + l15;
        const f32x4 Sv = nt ? S1 : S0;
#pragma unroll
        for (int r = 0; r < 4; ++r) {
          float pv;
          if (needmask) {
            int rowg = q0 + rowl + r;
            pv = (keyg <= rowg + 1) ? __expf(Sv[r] * SCALE) : 0.f;
          } else {
            pv = __expf(Sv[r] * SCALE);
          }
          z[mat][r] += pv;
          sP[buf][mat][(rowl + r) * 136 + wk * 32 + nt * 16 + l15] = (__bf16)pv;
        }
      }
    }
    __syncthreads();

    // PV: O += P @ V  (P A-frags from LDS; V B-frags direct from global Vt)
#pragma unroll
    for (int ks = 0; ks < 4; ++ks) {
      bf16x8 pf0 = *(const bf16x8*)(&sP[buf][0][(wm * 16 + l15) * 136 + ks * 32 + quad * 8]);
      bf16x8 pf1 = *(const bf16x8*)(&sP[buf][1][(wm * 16 + l15) * 136 + ks * 32 + quad * 8]);
#pragma unroll
      for (int nt = 0; nt < 2; ++nt) {
        bf16x8 vf = *(const bf16x8*)(Vtb + (size_t)(wk * 32 + nt * 16 + l15) * T_SEQ +
                                     k0 + ks * 32 + quad * 8);
        O[0][nt] = MFMA16(pf0, vf, O[0][nt], 0, 0, 0);
        O[1][nt] = MFMA16(pf1, vf, O[1][nt], 0, 0, 0);
      }
    }
    // no trailing barrier: sP is double-buffered
  }

  // ---- Z reduction ----
#pragma unroll
  for (int mat = 0; mat < 2; ++mat)
#pragma unroll
    for (int r = 0; r < 4; ++r)
      zb[mat][wm * 16 + quad * 4 + r][wk * 16 + l15] = z[mat][r];
  __syncthreads();
  if (tid < 64) {
    int mat = tid >> 5, row = tid & 31;
    float s = 0.f;
#pragma unroll
    for (int j = 0; j < 64; ++j) s += zb[mat][row][(j + tid) & 63];  // bank-spread
    zfin[mat][row] = s;
  }
  __syncthreads();

  // ---- epilogue: normalize + closed-form masked tail + pad rows ----
#pragma unroll
  for (int r = 0; r < 4; ++r) {
    const int rowl = wm * 16 + quad * 4 + r;
    const int rowg = q0 + rowl;
    const int nallow = min(rowg + 2, T_SEQ);
    const float nmask = (float)(T_SEQ - nallow);
    const float Z1 = zfin[0][rowl] + nmask;
    const float Z2 = zfin[1][rowl] + nmask;
    const float i1 = 1.f / Z1, i2 = lbd / Z2;
    const float tc = i1 - i2;
    const bool isp = (pad[b * T_SEQ + rowg] == 1);
#pragma unroll
    for (int nt = 0; nt < 2; ++nt) {
      const int col = wk * 32 + nt * 16 + l15;
      const float ct = cumb[(size_t)T_SEQ * HS + col];
      const float cn = cumb[(size_t)nallow * HS + col];
      float val = isp ? (pc * ct)
                      : (O[0][nt][r] * i1 - O[1][nt][r] * i2 + tc * (ct - cn));
      out[((size_t)b * T_SEQ + rowg) * HS + col] = val;
    }
  }
}

// ---------------------------------------------------------------------------
extern "C" void kernel_launch(void* const* d_in, const int* in_sizes, int n_in,
                              void* d_out, int out_size, void* d_ws, size_t ws_size,
                              hipStream_t stream) {
  (void)in_sizes; (void)n_in; (void)out_size; (void)ws_size;
  const float* q   = (const float*)d_in[0];
  const float* k   = (const float*)d_in[1];
  const float* v   = (const float*)d_in[2];
  const int*   pm  = (const int*)d_in[3];
  const float* Wq  = (const float*)d_in[4];
  const float* Wk  = (const float*)d_in[5];
  const float* Wv  = (const float*)d_in[6];
  const float* lq1 = (const float*)d_in[7];
  const float* lk1 = (const float*)d_in[8];
  const float* lq2 = (const float*)d_in[9];
  const float* lk2 = (const float*)d_in[10];
  float* out = (float*)d_out;
  char* ws = (char*)d_ws;

  // workspace layout (bytes)
  float*  lbd  = (float*)ws;                                   // 16
  __bf16* Wp   = (__bf16*)(ws + 16);                           // 40*32*64*8*2 = 1310720
  __bf16* Qp   = (__bf16*)(ws + 16 + 1310720);                 // 8*2048*256*2
  __bf16* Kp   = Qp + (size_t)NB * T_SEQ * 256;
  __bf16* Vp   = Kp + (size_t)NB * T_SEQ * 256;                // 8*2048*128*2
  __bf16* Vt   = Vp + (size_t)NB * T_SEQ * HS;
  float*  cum  = (float*)(Vt + (size_t)NB * T_SEQ * HS);       // 8*2049*128*4
  float*  csum = cum + (size_t)NB * (T_SEQ + 1) * HS;          // 8*16*128*4

  lambda_kernel<<<dim3(1), dim3(128), 0, stream>>>(lq1, lk1, lq2, lk2, lbd);
  pack_w<<<dim3(40), dim3(256), 0, stream>>>(Wq, Wk, Wv, Wp);
  proj_mfma<<<dim3(384), dim3(256), 0, stream>>>(q, k, v, Wp, Qp, Kp, Vp, Vt);
  vcsum_a<<<dim3(128), dim3(128), 0, stream>>>(Vp, csum);
  vcsum_b<<<dim3(128), dim3(128), 0, stream>>>(Vp, csum, cum);
  attn_mfma<<<dim3(512), dim3(512), 0, stream>>>(Qp, Kp, Vt, cum, pm, lbd, out);
}

// Round 5
// 373.889 us; speedup vs baseline: 1.0644x; 1.0148x over previous
//
#include <hip/hip_runtime.h>
#include <math.h>

// ---------------------------------------------------------------------------
// DiffHead, MFMA edition, round 11: kill exposed K/V load latency in attn.
//   r10 counters: 117us, MfmaUtil 6.2, VALU 9.7 -> 84% stall. Critical path =
//   big-tile blocks doing up to 16 serial k-iterations, each ~12K cycles
//   because 16 K-frags are loaded from L2 and consumed immediately (full
//   latency exposed, twice per iteration incl. V in PV).
//   Changes (attn only):
//   1. Register rotation: kf[16]/vf[8] frag buffers; consume K(kt) in QK then
//      issue K(kt+1) loads into the same regs (WAR reuse) -> latency hides
//      under exp+barrier+PV. V(kt+1) issued after PV(kt), hides under next QK.
//   2. LPT block order: ti = 63 - (p>>3) (longest first) -> makespan ~=
//      total/256 CUs, robust to dispatch order. b = p&7 keeps batch->XCD L2
//      locality (per-batch working set ~3.5MB < 4MB XCD L2).
//   Spill tripwire: if WRITE_SIZE >> 8.2MB next round, allocator clamped VGPR
//   again (r7 failure mode) -> revert rotation.
// Math identical: fill=1e-9 => exp(fill*scale)==1.0f -> masked tail
//   closed-form via V prefix sums; padded rows closed form; fixed shift m=0.
// MFMA 16x16x32_bf16 layouts: A/B lane: m/n=lane&15, k=quad*8+j (16B contig);
//   C/D: col=lane&15, row=quad*4+reg.
// ---------------------------------------------------------------------------

#define T_SEQ 2048
#define NB 8
#define CDIM 1024
#define HS 128

constexpr float SCALE = 0.08838834764831845f;   // 128^-0.5

typedef float f32x4 __attribute__((ext_vector_type(4)));
typedef __bf16 bf16x8 __attribute__((ext_vector_type(8)));
typedef unsigned int u32;

#define MFMA16 __builtin_amdgcn_mfma_f32_16x16x32_bf16

__device__ __forceinline__ void gld16(const void* g, void* l) {
  __builtin_amdgcn_global_load_lds(
      (const __attribute__((address_space(1))) u32*)g,
      (__attribute__((address_space(3))) u32*)l, 16, 0, 0);
}

__device__ __forceinline__ bf16x8 cvt8(f32x4 lo, f32x4 hi) {
  bf16x8 r;
  r[0] = (__bf16)lo.x; r[1] = (__bf16)lo.y; r[2] = (__bf16)lo.z; r[3] = (__bf16)lo.w;
  r[4] = (__bf16)hi.x; r[5] = (__bf16)hi.y; r[6] = (__bf16)hi.z; r[7] = (__bf16)hi.w;
  return r;
}

// --------------------------- lambda = exp(lq1.lk1) - exp(lq2.lk2) + 0.8 -----
__global__ __launch_bounds__(128) void lambda_kernel(
    const float* __restrict__ lq1, const float* __restrict__ lk1,
    const float* __restrict__ lq2, const float* __restrict__ lk2,
    float* __restrict__ lbd) {
  __shared__ float r1[128], r2[128];
  int t = threadIdx.x;
  r1[t] = lq1[t] * lk1[t];
  r2[t] = lq2[t] * lk2[t];
  __syncthreads();
  for (int s = 64; s > 0; s >>= 1) {
    if (t < s) { r1[t] += r1[t + s]; r2[t] += r2[t + s]; }
    __syncthreads();
  }
  if (t == 0) *lbd = expf(r1[0]) - expf(r2[0]) + 0.8f;
}

// --------------------------- pack W: lane-contiguous B-frag chunks ----------
// Wp chunk (ntile 0..39, ks 0..31): 1KB = 64 lanes x 16B; lane (quad,l15):
//   n = ntile*16 + l15, k = ks*32 + quad*8 .. +7.  ntile: q 0-15, k 16-31, v 32-39.
__global__ __launch_bounds__(256) void pack_w(
    const float* __restrict__ Wq, const float* __restrict__ Wk,
    const float* __restrict__ Wv, __bf16* __restrict__ Wp) {
  int nt = blockIdx.x;  // 0..39
  const float* W; int colbase, N;
  if (nt < 16)      { W = Wq; colbase = nt * 16;        N = 256; }
  else if (nt < 32) { W = Wk; colbase = (nt - 16) * 16; N = 256; }
  else              { W = Wv; colbase = (nt - 32) * 16; N = 128; }
  int tid = threadIdx.x;
#pragma unroll
  for (int i = 0; i < 8; ++i) {
    int u = tid + 256 * i;            // 2048 = 32 ks * 64 lanes
    int ks = u >> 6, lane = u & 63;
    int l15 = lane & 15, quad = lane >> 4;
    bf16x8 pk;
#pragma unroll
    for (int j = 0; j < 8; ++j)
      pk[j] = (__bf16)W[(size_t)(ks * 32 + quad * 8 + j) * N + colbase + l15];
    *(bf16x8*)(Wp + ((size_t)(nt * 32 + ks) * 64 + lane) * 8) = pk;
  }
}

// --------------------------- projection GEMM body (templated on NT) ---------
// NT = n-tiles of 16 (16 for q/k, 8 for v); NTG = n-tile offset into Wp.
// Block = 128 rows x all N. BK=32 double-buffered global_load_lds staging.
template<int NT, int NTG>
__device__ __forceinline__ void proj_body(
    const float* __restrict__ Ablk, const __bf16* __restrict__ Wp,
    __bf16* __restrict__ outp, __bf16* __restrict__ Vt,
    int rows0, char* smem) {
  float*  sA = (float*)smem;                    // 2 x 4096 floats (32KB)
  __bf16* sB = (__bf16*)(smem + 32768);         // 2 x 8192 bf16  (32KB)
  const int tid = threadIdx.x;
  const int lane = tid & 63, wave = tid >> 6;
  const int l15 = lane & 15, quad = lane >> 4;
  const int arow = lane >> 3;                   // A-staging row-within-8
  const int ac16 = (lane & 7) ^ arow;           // XOR swizzle (row&7)

  f32x4 acc0[NT], acc1[NT];
#pragma unroll
  for (int j = 0; j < NT; ++j) {
    acc0[j] = (f32x4){0.f, 0.f, 0.f, 0.f};
    acc1[j] = (f32x4){0.f, 0.f, 0.f, 0.f};
  }

  auto stage_ks = [&](int ks, int buf) {
    const float* gA = Ablk + ks * 32;
    float* lA = sA + buf * 4096;
#pragma unroll
    for (int i = 0; i < 4; ++i) {
      int li = wave * 4 + i;                     // 16 loads, 8 rows each
      gld16(gA + (size_t)(li * 8 + arow) * CDIM + ac16 * 4, lA + li * 256);
    }
    __bf16* lB = sB + buf * 8192;
#pragma unroll
    for (int i = 0; i < 4; ++i) {
      int ntl = wave * 4 + i;                    // one 1KB chunk per n-tile
      if (ntl < NT)
        gld16(Wp + ((size_t)((NTG + ntl) * 32 + ks) * 64 + lane) * 8,
              lB + ntl * 512);
    }
  };

  stage_ks(0, 0);
  for (int ks = 0; ks < 32; ++ks) {
    const int buf = ks & 1;
    __syncthreads();
    // A frags (un-swizzle: chunk c of row r lives at LDS pos c^(r&7))
    const float* lA = sA + buf * 4096;
    int r0 = wave * 32 + l15;
    f32x4 lo0 = *(const f32x4*)(lA + r0 * 32 + (((quad * 2)     ^ (l15 & 7)) * 4));
    f32x4 hi0 = *(const f32x4*)(lA + r0 * 32 + (((quad * 2 + 1) ^ (l15 & 7)) * 4));
    bf16x8 af0 = cvt8(lo0, hi0);
    int r1 = r0 + 16;
    f32x4 lo1 = *(const f32x4*)(lA + r1 * 32 + (((quad * 2)     ^ (l15 & 7)) * 4));
    f32x4 hi1 = *(const f32x4*)(lA + r1 * 32 + (((quad * 2 + 1) ^ (l15 & 7)) * 4));
    bf16x8 af1 = cvt8(lo1, hi1);
    if (ks < 31) stage_ks(ks + 1, buf ^ 1);      // prefetch overlaps MFMA
    const __bf16* lB = sB + buf * 8192;
#pragma unroll
    for (int nt = 0; nt < NT; ++nt) {            // constexpr trip count!
      bf16x8 bf = *(const bf16x8*)(lB + nt * 512 + lane * 8);
      acc0[nt] = MFMA16(af0, bf, acc0[nt], 0, 0, 0);
      acc1[nt] = MFMA16(af1, bf, acc1[nt], 0, 0, 0);
    }
  }

  // ---- epilogue: C through LDS tile -> coalesced 16B stores ----
  __syncthreads();
  __bf16* tile = (__bf16*)smem;                  // [128][136] bf16 (34.8KB)
  constexpr int N = NT * 16;
#pragma unroll
  for (int half = 0; half < (NT >> 3); ++half) {
#pragma unroll
    for (int ntl = 0; ntl < 8; ++ntl) {
      f32x4 a0 = acc0[half * 8 + ntl];
      f32x4 a1 = acc1[half * 8 + ntl];
#pragma unroll
      for (int r = 0; r < 4; ++r) {
        tile[(wave * 32 + quad * 4 + r) * 136 + ntl * 16 + l15] = (__bf16)a0[r];
        tile[(wave * 32 + 16 + quad * 4 + r) * 136 + ntl * 16 + l15] = (__bf16)a1[r];
      }
    }
    __syncthreads();
#pragma unroll
    for (int i = 0; i < 8; ++i) {
      int u = tid + 256 * i;                     // 2048 chunks: 128 rows x 16x16B
      int row = u >> 4, c8 = u & 15;
      bf16x8 val = *(const bf16x8*)(tile + row * 136 + c8 * 8);
      *(bf16x8*)(outp + (size_t)(rows0 + row) * N + half * 128 + c8 * 8) = val;
    }
    if constexpr (NT == 8) {                     // v: also Vt[b][c][t] via transpose
      int b = rows0 >> 11, t0 = rows0 & 2047;
#pragma unroll
      for (int i = 0; i < 8; ++i) {
        int u = tid + 256 * i;                   // 2048 = 16 tc x 128 c
        int tc = u & 15, c = u >> 4;
        bf16x8 pk;
#pragma unroll
        for (int j = 0; j < 8; ++j) pk[j] = tile[(tc * 8 + j) * 136 + c];
        *(bf16x8*)(Vt + ((size_t)(b * 128 + c)) * T_SEQ + t0 + tc * 8) = pk;
      }
    }
    __syncthreads();
  }
}

// 384 blocks x 256 thr. Blocks 0..127: q->Q(N=256); 128..255: k->K; 256..383: v->V(+Vt).
__global__ __launch_bounds__(256, 2) void proj_mfma(
    const float* __restrict__ qin, const float* __restrict__ kin,
    const float* __restrict__ vin, const __bf16* __restrict__ Wp,
    __bf16* __restrict__ Qo, __bf16* __restrict__ Ko,
    __bf16* __restrict__ Vo, __bf16* __restrict__ Vt) {
  __shared__ char smem[65536];
  const int blk = blockIdx.x;
  const int rows0 = (blk & 127) * 128;
  if (blk < 128)
    proj_body<16, 0>(qin + (size_t)rows0 * CDIM, Wp, Qo, nullptr, rows0, smem);
  else if (blk < 256)
    proj_body<16, 16>(kin + (size_t)rows0 * CDIM, Wp, Ko, nullptr, rows0, smem);
  else
    proj_body<8, 32>(vin + (size_t)rows0 * CDIM, Wp, Vo, Vt, rows0, smem);
}

// --------------------------- V prefix sums (bf16 in, fp32 out) --------------
__global__ __launch_bounds__(128) void vcsum_a(const __bf16* __restrict__ V,
                                               float* __restrict__ csum) {
  int blk = blockIdx.x; int b = blk >> 4, ch = blk & 15;
  int c = threadIdx.x;
  const __bf16* vp = V + ((size_t)b * T_SEQ + ch * 128) * HS + c;
  float s = 0.f;
#pragma unroll 4
  for (int t = 0; t < 128; ++t) s += (float)vp[(size_t)t * HS];
  csum[(size_t)blk * HS + c] = s;
}

__global__ __launch_bounds__(128) void vcsum_b(const __bf16* __restrict__ V,
                                               const float* __restrict__ csum,
                                               float* __restrict__ cum) {
  int blk = blockIdx.x; int b = blk >> 4, ch = blk & 15;
  int c = threadIdx.x;
  float run = 0.f;
  for (int j = 0; j < ch; ++j) run += csum[(size_t)(b * 16 + j) * HS + c];
  const __bf16* vp = V + ((size_t)b * T_SEQ + ch * 128) * HS + c;
  float* cp = cum + ((size_t)b * (T_SEQ + 1) + ch * 128) * HS + c;
  if (ch == 0) cp[0] = 0.f;
#pragma unroll 4
  for (int t = 0; t < 128; ++t) {
    run += (float)vp[(size_t)t * HS];
    cp[(size_t)(t + 1) * HS] = run;
  }
}

// --------------------------- attention (bf16 MFMA, flash-style) -------------
// 512 blocks x 512 thr (8 waves: wm = wave>>2 m-split, wk = wave&3 key-split).
// One 32-row q-tile per block; ti = 63 - (p>>3): LPT (longest first).
// b = p&7: batch->XCD L2 locality. K/V frags register-rotated: loads for
// iteration kt+1 issued while kt computes -> no exposed L2 latency.
__global__ __launch_bounds__(512, 2) void attn_mfma(
    const __bf16* __restrict__ Q, const __bf16* __restrict__ K,
    const __bf16* __restrict__ Vt, const float* __restrict__ cum,
    const int* __restrict__ pad, const float* __restrict__ lbdp,
    float* __restrict__ out) {
  __shared__ __bf16 sQ[32 * 264];            // 32 rows x 256, stride 264 (pad)
  __shared__ __bf16 sP[2][2][32 * 136];      // [buf][mat][row*136+key], pad 8
  __shared__ float zb[2][32][64];
  __shared__ float zfin[2][32];

  const int tid = threadIdx.x;
  const int lane = tid & 63, wave = tid >> 6;
  const int wm = wave >> 2, wk = wave & 3;
  const int l15 = lane & 15, quad = lane >> 4;

  const int p = blockIdx.x;
  const int b = p & 7;
  const int ti = 63 - (p >> 3);              // LPT order: big tiles first
  const int q0 = ti * 32;
  const float lbd = *lbdp;
  const __bf16* Qb = Q + (size_t)b * T_SEQ * 256;
  const __bf16* Kb = K + (size_t)b * T_SEQ * 256;
  const __bf16* Vtb = Vt + (size_t)b * HS * T_SEQ;
  const float* cumb = cum + (size_t)b * (T_SEQ + 1) * HS;
  const float pc = (1.f - lbd) * (1.f / (float)T_SEQ);

  const int lastkey = q0 + 32;             // max allowed key (row q0+31, +1 lookahead)
  const int nkt = (min(lastkey, T_SEQ - 1) >> 7) + 1;

  // ---- rotated K/V fragment registers ----
  bf16x8 kf[2][2][4];   // [mat][half:+0/+16 keys][kstep]  (64 VGPRs)
  bf16x8 vf[2][4];      // [nt][kstep]                     (32 VGPRs)
  auto loadK = [&](int k0) {
#pragma unroll
    for (int mat = 0; mat < 2; ++mat) {
      const __bf16* kp = Kb + (size_t)(k0 + wk * 32 + l15) * 256 + mat * 128 + quad * 8;
#pragma unroll
      for (int s = 0; s < 4; ++s) {
        kf[mat][0][s] = *(const bf16x8*)(kp + s * 32);
        kf[mat][1][s] = *(const bf16x8*)(kp + 16 * 256 + s * 32);
      }
    }
  };
  auto loadV = [&](int k0) {
#pragma unroll
    for (int nt = 0; nt < 2; ++nt)
#pragma unroll
      for (int ks = 0; ks < 4; ++ks)
        vf[nt][ks] = *(const bf16x8*)(Vtb + (size_t)(wk * 32 + nt * 16 + l15) * T_SEQ +
                                      k0 + ks * 32 + quad * 8);
  };
  loadK(0);        // issued before Q staging: latency hides under stage+barrier
  loadV(0);

  // ---- stage Q tile (16KB) ----
#pragma unroll
  for (int i = 0; i < 2; ++i) {
    int c = tid + 512 * i;                 // 1024 16B-chunks
    int row = c >> 5, c16 = c & 31;
    *(f32x4*)(&sQ[row * 264 + c16 * 8]) =
        *(const f32x4*)(Qb + (size_t)(q0 + row) * 256 + c16 * 8);
  }
  __syncthreads();

  // ---- preload Q A-frags (rows wm*16+l15, both planes, 4 ksteps) ----
  bf16x8 qf[2][4];
  {
    const int row = wm * 16 + l15;
#pragma unroll
    for (int pl = 0; pl < 2; ++pl)
#pragma unroll
      for (int s = 0; s < 4; ++s)
        qf[pl][s] = *(const bf16x8*)(&sQ[row * 264 + pl * 128 + s * 32 + quad * 8]);
  }

  f32x4 O[2][2];
#pragma unroll
  for (int i = 0; i < 2; ++i)
#pragma unroll
    for (int j = 0; j < 2; ++j) O[i][j] = (f32x4){0.f, 0.f, 0.f, 0.f};
  float z[2][4] = {};

  for (int kt = 0; kt < nkt; ++kt) {
    const int k0 = kt << 7;
    const bool needmask = (k0 + 127 > q0 + 1);
    const int buf = kt & 1;

    // ---- QK^T: consume kf (loaded last iteration / prologue) ----
    f32x4 S[2][2];
#pragma unroll
    for (int mat = 0; mat < 2; ++mat) {
      S[mat][0] = (f32x4){0.f, 0.f, 0.f, 0.f};
      S[mat][1] = (f32x4){0.f, 0.f, 0.f, 0.f};
#pragma unroll
      for (int s = 0; s < 4; ++s) {
        S[mat][0] = MFMA16(qf[mat][s], kf[mat][0][s], S[mat][0], 0, 0, 0);
        S[mat][1] = MFMA16(qf[mat][s], kf[mat][1][s], S[mat][1], 0, 0, 0);
      }
    }
    // prefetch next K into the same regs (WAR): hides under exp+barrier+PV
    if (kt + 1 < nkt) loadK(k0 + 128);

    // ---- exp + z partials + write P (bf16) to LDS ----
    const int rowl = wm * 16 + quad * 4;
#pragma unroll
    for (int mat = 0; mat < 2; ++mat)
#pragma unroll
      for (int nt = 0; nt < 2; ++nt) {
        const int keyg = k0 + wk * 32 + nt * 16 + l15;
#pragma unroll
        for (int r = 0; r < 4; ++r) {
          float pv;
          if (needmask) {
            int rowg = q0 + rowl + r;
            pv = (keyg <= rowg + 1) ? __expf(S[mat][nt][r] * SCALE) : 0.f;
          } else {
            pv = __expf(S[mat][nt][r] * SCALE);
          }
          z[mat][r] += pv;
          sP[buf][mat][(rowl + r) * 136 + wk * 32 + nt * 16 + l15] = (__bf16)pv;
        }
      }
    __syncthreads();

    // ---- PV: O += P @ V (P from LDS, V from rotated regs) ----
#pragma unroll
    for (int ks = 0; ks < 4; ++ks) {
      bf16x8 pf0 = *(const bf16x8*)(&sP[buf][0][(wm * 16 + l15) * 136 + ks * 32 + quad * 8]);
      bf16x8 pf1 = *(const bf16x8*)(&sP[buf][1][(wm * 16 + l15) * 136 + ks * 32 + quad * 8]);
#pragma unroll
      for (int nt = 0; nt < 2; ++nt) {
        O[0][nt] = MFMA16(pf0, vf[nt][ks], O[0][nt], 0, 0, 0);
        O[1][nt] = MFMA16(pf1, vf[nt][ks], O[1][nt], 0, 0, 0);
      }
    }
    // prefetch next V (hides under next iteration's QK phase)
    if (kt + 1 < nkt) loadV(k0 + 128);
    // no trailing barrier: sP is double-buffered
  }

  // ---- Z reduction ----
#pragma unroll
  for (int mat = 0; mat < 2; ++mat)
#pragma unroll
    for (int r = 0; r < 4; ++r)
      zb[mat][wm * 16 + quad * 4 + r][wk * 16 + l15] = z[mat][r];
  __syncthreads();
  if (tid < 64) {
    int mat = tid >> 5, row = tid & 31;
    float s = 0.f;
#pragma unroll
    for (int j = 0; j < 64; ++j) s += zb[mat][row][(j + tid) & 63];  // bank-spread
    zfin[mat][row] = s;
  }
  __syncthreads();

  // ---- epilogue: normalize + closed-form masked tail + pad rows ----
#pragma unroll
  for (int r = 0; r < 4; ++r) {
    const int rowl = wm * 16 + quad * 4 + r;
    const int rowg = q0 + rowl;
    const int nallow = min(rowg + 2, T_SEQ);
    const float nmask = (float)(T_SEQ - nallow);
    const float Z1 = zfin[0][rowl] + nmask;
    const float Z2 = zfin[1][rowl] + nmask;
    const float i1 = 1.f / Z1, i2 = lbd / Z2;
    const float tc = i1 - i2;
    const bool isp = (pad[b * T_SEQ + rowg] == 1);
#pragma unroll
    for (int nt = 0; nt < 2; ++nt) {
      const int col = wk * 32 + nt * 16 + l15;
      const float ct = cumb[(size_t)T_SEQ * HS + col];
      const float cn = cumb[(size_t)nallow * HS + col];
      float val = isp ? (pc * ct)
                      : (O[0][nt][r] * i1 - O[1][nt][r] * i2 + tc * (ct - cn));
      out[((size_t)b * T_SEQ + rowg) * HS + col] = val;
    }
  }
}

// ---------------------------------------------------------------------------
extern "C" void kernel_launch(void* const* d_in, const int* in_sizes, int n_in,
                              void* d_out, int out_size, void* d_ws, size_t ws_size,
                              hipStream_t stream) {
  (void)in_sizes; (void)n_in; (void)out_size; (void)ws_size;
  const float* q   = (const float*)d_in[0];
  const float* k   = (const float*)d_in[1];
  const float* v   = (const float*)d_in[2];
  const int*   pm  = (const int*)d_in[3];
  const float* Wq  = (const float*)d_in[4];
  const float* Wk  = (const float*)d_in[5];
  const float* Wv  = (const float*)d_in[6];
  const float* lq1 = (const float*)d_in[7];
  const float* lk1 = (const float*)d_in[8];
  const float* lq2 = (const float*)d_in[9];
  const float* lk2 = (const float*)d_in[10];
  float* out = (float*)d_out;
  char* ws = (char*)d_ws;

  // workspace layout (bytes)
  float*  lbd  = (float*)ws;                                   // 16
  __bf16* Wp   = (__bf16*)(ws + 16);                           // 40*32*64*8*2 = 1310720
  __bf16* Qp   = (__bf16*)(ws + 16 + 1310720);                 // 8*2048*256*2
  __bf16* Kp   = Qp + (size_t)NB * T_SEQ * 256;
  __bf16* Vp   = Kp + (size_t)NB * T_SEQ * 256;                // 8*2048*128*2
  __bf16* Vt   = Vp + (size_t)NB * T_SEQ * HS;
  float*  cum  = (float*)(Vt + (size_t)NB * T_SEQ * HS);       // 8*2049*128*4
  float*  csum = cum + (size_t)NB * (T_SEQ + 1) * HS;          // 8*16*128*4

  lambda_kernel<<<dim3(1), dim3(128), 0, stream>>>(lq1, lk1, lq2, lk2, lbd);
  pack_w<<<dim3(40), dim3(256), 0, stream>>>(Wq, Wk, Wv, Wp);
  proj_mfma<<<dim3(384), dim3(256), 0, stream>>>(q, k, v, Wp, Qp, Kp, Vp, Vt);
  vcsum_a<<<dim3(128), dim3(128), 0, stream>>>(Vp, csum);
  vcsum_b<<<dim3(128), dim3(128), 0, stream>>>(Vp, csum, cum);
  attn_mfma<<<dim3(512), dim3(512), 0, stream>>>(Qp, Kp, Vt, cum, pm, lbd, out);
}

// Round 6
// 370.910 us; speedup vs baseline: 1.0729x; 1.0080x over previous
//
#include <hip/hip_runtime.h>
#include <math.h>

// ---------------------------------------------------------------------------
// DiffHead, MFMA edition, round 12: make the r11 prefetch actually work.
//   r11 counters (119us, MfmaUtil 6.1, WRITE 8.2MB, VGPR 104): rotation
//   materialized, no spill -- but no speedup. Root cause: __syncthreads()
//   compiles to s_waitcnt vmcnt(0) lgkmcnt(0) + s_barrier, so the in-loop
//   barrier drains the just-issued K/V prefetch loads; every iteration still
//   pays the full L2 round-trip serially (~12K cy/iter vs ~700 cy of issue).
//   Fix: counted-wait barrier = { asm s_waitcnt lgkmcnt(0);
//   __builtin_amdgcn_s_barrier(); sched_barrier(0) }  -- LDS writes are made
//   visible (lgkmcnt) but vmcnt stays free, so register prefetches stay in
//   flight ACROSS the barrier (HK/AITER pattern, verified in the 8-phase
//   template). Backend still inserts precise vmcnt waits at kf/vf use sites.
//   Applied to the Q-stage barrier and the in-loop P barrier; epilogue
//   Z-reduction keeps plain __syncthreads().
// Math identical: fill=1e-9 => exp(fill*scale)==1.0f -> masked tail
//   closed-form via V prefix sums; padded rows closed form; fixed shift m=0.
// MFMA 16x16x32_bf16 layouts: A/B lane: m/n=lane&15, k=quad*8+j (16B contig);
//   C/D: col=lane&15, row=quad*4+reg.
// ---------------------------------------------------------------------------

#define T_SEQ 2048
#define NB 8
#define CDIM 1024
#define HS 128

constexpr float SCALE = 0.08838834764831845f;   // 128^-0.5

typedef float f32x4 __attribute__((ext_vector_type(4)));
typedef __bf16 bf16x8 __attribute__((ext_vector_type(8)));
typedef unsigned int u32;

#define MFMA16 __builtin_amdgcn_mfma_f32_16x16x32_bf16

__device__ __forceinline__ void gld16(const void* g, void* l) {
  __builtin_amdgcn_global_load_lds(
      (const __attribute__((address_space(1))) u32*)g,
      (__attribute__((address_space(3))) u32*)l, 16, 0, 0);
}

// barrier that makes LDS traffic visible but leaves global loads in flight
__device__ __forceinline__ void wg_barrier_lds() {
  asm volatile("s_waitcnt lgkmcnt(0)" ::: "memory");
  __builtin_amdgcn_s_barrier();
  __builtin_amdgcn_sched_barrier(0);
}

__device__ __forceinline__ bf16x8 cvt8(f32x4 lo, f32x4 hi) {
  bf16x8 r;
  r[0] = (__bf16)lo.x; r[1] = (__bf16)lo.y; r[2] = (__bf16)lo.z; r[3] = (__bf16)lo.w;
  r[4] = (__bf16)hi.x; r[5] = (__bf16)hi.y; r[6] = (__bf16)hi.z; r[7] = (__bf16)hi.w;
  return r;
}

// --------------------------- lambda = exp(lq1.lk1) - exp(lq2.lk2) + 0.8 -----
__global__ __launch_bounds__(128) void lambda_kernel(
    const float* __restrict__ lq1, const float* __restrict__ lk1,
    const float* __restrict__ lq2, const float* __restrict__ lk2,
    float* __restrict__ lbd) {
  __shared__ float r1[128], r2[128];
  int t = threadIdx.x;
  r1[t] = lq1[t] * lk1[t];
  r2[t] = lq2[t] * lk2[t];
  __syncthreads();
  for (int s = 64; s > 0; s >>= 1) {
    if (t < s) { r1[t] += r1[t + s]; r2[t] += r2[t + s]; }
    __syncthreads();
  }
  if (t == 0) *lbd = expf(r1[0]) - expf(r2[0]) + 0.8f;
}

// --------------------------- pack W: lane-contiguous B-frag chunks ----------
// Wp chunk (ntile 0..39, ks 0..31): 1KB = 64 lanes x 16B; lane (quad,l15):
//   n = ntile*16 + l15, k = ks*32 + quad*8 .. +7.  ntile: q 0-15, k 16-31, v 32-39.
__global__ __launch_bounds__(256) void pack_w(
    const float* __restrict__ Wq, const float* __restrict__ Wk,
    const float* __restrict__ Wv, __bf16* __restrict__ Wp) {
  int nt = blockIdx.x;  // 0..39
  const float* W; int colbase, N;
  if (nt < 16)      { W = Wq; colbase = nt * 16;        N = 256; }
  else if (nt < 32) { W = Wk; colbase = (nt - 16) * 16; N = 256; }
  else              { W = Wv; colbase = (nt - 32) * 16; N = 128; }
  int tid = threadIdx.x;
#pragma unroll
  for (int i = 0; i < 8; ++i) {
    int u = tid + 256 * i;            // 2048 = 32 ks * 64 lanes
    int ks = u >> 6, lane = u & 63;
    int l15 = lane & 15, quad = lane >> 4;
    bf16x8 pk;
#pragma unroll
    for (int j = 0; j < 8; ++j)
      pk[j] = (__bf16)W[(size_t)(ks * 32 + quad * 8 + j) * N + colbase + l15];
    *(bf16x8*)(Wp + ((size_t)(nt * 32 + ks) * 64 + lane) * 8) = pk;
  }
}

// --------------------------- projection GEMM body (templated on NT) ---------
// NT = n-tiles of 16 (16 for q/k, 8 for v); NTG = n-tile offset into Wp.
// Block = 128 rows x all N. BK=32 double-buffered global_load_lds staging.
template<int NT, int NTG>
__device__ __forceinline__ void proj_body(
    const float* __restrict__ Ablk, const __bf16* __restrict__ Wp,
    __bf16* __restrict__ outp, __bf16* __restrict__ Vt,
    int rows0, char* smem) {
  float*  sA = (float*)smem;                    // 2 x 4096 floats (32KB)
  __bf16* sB = (__bf16*)(smem + 32768);         // 2 x 8192 bf16  (32KB)
  const int tid = threadIdx.x;
  const int lane = tid & 63, wave = tid >> 6;
  const int l15 = lane & 15, quad = lane >> 4;
  const int arow = lane >> 3;                   // A-staging row-within-8
  const int ac16 = (lane & 7) ^ arow;           // XOR swizzle (row&7)

  f32x4 acc0[NT], acc1[NT];
#pragma unroll
  for (int j = 0; j < NT; ++j) {
    acc0[j] = (f32x4){0.f, 0.f, 0.f, 0.f};
    acc1[j] = (f32x4){0.f, 0.f, 0.f, 0.f};
  }

  auto stage_ks = [&](int ks, int buf) {
    const float* gA = Ablk + ks * 32;
    float* lA = sA + buf * 4096;
#pragma unroll
    for (int i = 0; i < 4; ++i) {
      int li = wave * 4 + i;                     // 16 loads, 8 rows each
      gld16(gA + (size_t)(li * 8 + arow) * CDIM + ac16 * 4, lA + li * 256);
    }
    __bf16* lB = sB + buf * 8192;
#pragma unroll
    for (int i = 0; i < 4; ++i) {
      int ntl = wave * 4 + i;                    // one 1KB chunk per n-tile
      if (ntl < NT)
        gld16(Wp + ((size_t)((NTG + ntl) * 32 + ks) * 64 + lane) * 8,
              lB + ntl * 512);
    }
  };

  stage_ks(0, 0);
  for (int ks = 0; ks < 32; ++ks) {
    const int buf = ks & 1;
    __syncthreads();
    // A frags (un-swizzle: chunk c of row r lives at LDS pos c^(r&7))
    const float* lA = sA + buf * 4096;
    int r0 = wave * 32 + l15;
    f32x4 lo0 = *(const f32x4*)(lA + r0 * 32 + (((quad * 2)     ^ (l15 & 7)) * 4));
    f32x4 hi0 = *(const f32x4*)(lA + r0 * 32 + (((quad * 2 + 1) ^ (l15 & 7)) * 4));
    bf16x8 af0 = cvt8(lo0, hi0);
    int r1 = r0 + 16;
    f32x4 lo1 = *(const f32x4*)(lA + r1 * 32 + (((quad * 2)     ^ (l15 & 7)) * 4));
    f32x4 hi1 = *(const f32x4*)(lA + r1 * 32 + (((quad * 2 + 1) ^ (l15 & 7)) * 4));
    bf16x8 af1 = cvt8(lo1, hi1);
    if (ks < 31) stage_ks(ks + 1, buf ^ 1);      // prefetch overlaps MFMA
    const __bf16* lB = sB + buf * 8192;
#pragma unroll
    for (int nt = 0; nt < NT; ++nt) {            // constexpr trip count!
      bf16x8 bf = *(const bf16x8*)(lB + nt * 512 + lane * 8);
      acc0[nt] = MFMA16(af0, bf, acc0[nt], 0, 0, 0);
      acc1[nt] = MFMA16(af1, bf, acc1[nt], 0, 0, 0);
    }
  }

  // ---- epilogue: C through LDS tile -> coalesced 16B stores ----
  __syncthreads();
  __bf16* tile = (__bf16*)smem;                  // [128][136] bf16 (34.8KB)
  constexpr int N = NT * 16;
#pragma unroll
  for (int half = 0; half < (NT >> 3); ++half) {
#pragma unroll
    for (int ntl = 0; ntl < 8; ++ntl) {
      f32x4 a0 = acc0[half * 8 + ntl];
      f32x4 a1 = acc1[half * 8 + ntl];
#pragma unroll
      for (int r = 0; r < 4; ++r) {
        tile[(wave * 32 + quad * 4 + r) * 136 + ntl * 16 + l15] = (__bf16)a0[r];
        tile[(wave * 32 + 16 + quad * 4 + r) * 136 + ntl * 16 + l15] = (__bf16)a1[r];
      }
    }
    __syncthreads();
#pragma unroll
    for (int i = 0; i < 8; ++i) {
      int u = tid + 256 * i;                     // 2048 chunks: 128 rows x 16x16B
      int row = u >> 4, c8 = u & 15;
      bf16x8 val = *(const bf16x8*)(tile + row * 136 + c8 * 8);
      *(bf16x8*)(outp + (size_t)(rows0 + row) * N + half * 128 + c8 * 8) = val;
    }
    if constexpr (NT == 8) {                     // v: also Vt[b][c][t] via transpose
      int b = rows0 >> 11, t0 = rows0 & 2047;
#pragma unroll
      for (int i = 0; i < 8; ++i) {
        int u = tid + 256 * i;                   // 2048 = 16 tc x 128 c
        int tc = u & 15, c = u >> 4;
        bf16x8 pk;
#pragma unroll
        for (int j = 0; j < 8; ++j) pk[j] = tile[(tc * 8 + j) * 136 + c];
        *(bf16x8*)(Vt + ((size_t)(b * 128 + c)) * T_SEQ + t0 + tc * 8) = pk;
      }
    }
    __syncthreads();
  }
}

// 384 blocks x 256 thr. Blocks 0..127: q->Q(N=256); 128..255: k->K; 256..383: v->V(+Vt).
__global__ __launch_bounds__(256, 2) void proj_mfma(
    const float* __restrict__ qin, const float* __restrict__ kin,
    const float* __restrict__ vin, const __bf16* __restrict__ Wp,
    __bf16* __restrict__ Qo, __bf16* __restrict__ Ko,
    __bf16* __restrict__ Vo, __bf16* __restrict__ Vt) {
  __shared__ char smem[65536];
  const int blk = blockIdx.x;
  const int rows0 = (blk & 127) * 128;
  if (blk < 128)
    proj_body<16, 0>(qin + (size_t)rows0 * CDIM, Wp, Qo, nullptr, rows0, smem);
  else if (blk < 256)
    proj_body<16, 16>(kin + (size_t)rows0 * CDIM, Wp, Ko, nullptr, rows0, smem);
  else
    proj_body<8, 32>(vin + (size_t)rows0 * CDIM, Wp, Vo, Vt, rows0, smem);
}

// --------------------------- V prefix sums (bf16 in, fp32 out) --------------
__global__ __launch_bounds__(128) void vcsum_a(const __bf16* __restrict__ V,
                                               float* __restrict__ csum) {
  int blk = blockIdx.x; int b = blk >> 4, ch = blk & 15;
  int c = threadIdx.x;
  const __bf16* vp = V + ((size_t)b * T_SEQ + ch * 128) * HS + c;
  float s = 0.f;
#pragma unroll 4
  for (int t = 0; t < 128; ++t) s += (float)vp[(size_t)t * HS];
  csum[(size_t)blk * HS + c] = s;
}

__global__ __launch_bounds__(128) void vcsum_b(const __bf16* __restrict__ V,
                                               const float* __restrict__ csum,
                                               float* __restrict__ cum) {
  int blk = blockIdx.x; int b = blk >> 4, ch = blk & 15;
  int c = threadIdx.x;
  float run = 0.f;
  for (int j = 0; j < ch; ++j) run += csum[(size_t)(b * 16 + j) * HS + c];
  const __bf16* vp = V + ((size_t)b * T_SEQ + ch * 128) * HS + c;
  float* cp = cum + ((size_t)b * (T_SEQ + 1) + ch * 128) * HS + c;
  if (ch == 0) cp[0] = 0.f;
#pragma unroll 4
  for (int t = 0; t < 128; ++t) {
    run += (float)vp[(size_t)t * HS];
    cp[(size_t)(t + 1) * HS] = run;
  }
}

// --------------------------- attention (bf16 MFMA, flash-style) -------------
// 512 blocks x 512 thr (8 waves: wm = wave>>2 m-split, wk = wave&3 key-split).
// One 32-row q-tile per block; ti = 63 - (p>>3): LPT (longest first).
// b = p&7: batch->XCD L2 locality. K/V frags register-rotated; counted-wait
// barriers (lgkmcnt only) let the prefetch loads stay in flight across the
// in-loop barrier -> no exposed L2 latency in steady state.
__global__ __launch_bounds__(512, 2) void attn_mfma(
    const __bf16* __restrict__ Q, const __bf16* __restrict__ K,
    const __bf16* __restrict__ Vt, const float* __restrict__ cum,
    const int* __restrict__ pad, const float* __restrict__ lbdp,
    float* __restrict__ out) {
  __shared__ __bf16 sQ[32 * 264];            // 32 rows x 256, stride 264 (pad)
  __shared__ __bf16 sP[2][2][32 * 136];      // [buf][mat][row*136+key], pad 8
  __shared__ float zb[2][32][64];
  __shared__ float zfin[2][32];

  const int tid = threadIdx.x;
  const int lane = tid & 63, wave = tid >> 6;
  const int wm = wave >> 2, wk = wave & 3;
  const int l15 = lane & 15, quad = lane >> 4;

  const int p = blockIdx.x;
  const int b = p & 7;
  const int ti = 63 - (p >> 3);              // LPT order: big tiles first
  const int q0 = ti * 32;
  const float lbd = *lbdp;
  const __bf16* Qb = Q + (size_t)b * T_SEQ * 256;
  const __bf16* Kb = K + (size_t)b * T_SEQ * 256;
  const __bf16* Vtb = Vt + (size_t)b * HS * T_SEQ;
  const float* cumb = cum + (size_t)b * (T_SEQ + 1) * HS;
  const float pc = (1.f - lbd) * (1.f / (float)T_SEQ);

  const int lastkey = q0 + 32;             // max allowed key (row q0+31, +1 lookahead)
  const int nkt = (min(lastkey, T_SEQ - 1) >> 7) + 1;

  // ---- rotated K/V fragment registers ----
  bf16x8 kf[2][2][4];   // [mat][half:+0/+16 keys][kstep]  (64 VGPRs)
  bf16x8 vf[2][4];      // [nt][kstep]                     (32 VGPRs)
  auto loadK = [&](int k0) {
#pragma unroll
    for (int mat = 0; mat < 2; ++mat) {
      const __bf16* kp = Kb + (size_t)(k0 + wk * 32 + l15) * 256 + mat * 128 + quad * 8;
#pragma unroll
      for (int s = 0; s < 4; ++s) {
        kf[mat][0][s] = *(const bf16x8*)(kp + s * 32);
        kf[mat][1][s] = *(const bf16x8*)(kp + 16 * 256 + s * 32);
      }
    }
  };
  auto loadV = [&](int k0) {
#pragma unroll
    for (int nt = 0; nt < 2; ++nt)
#pragma unroll
      for (int ks = 0; ks < 4; ++ks)
        vf[nt][ks] = *(const bf16x8*)(Vtb + (size_t)(wk * 32 + nt * 16 + l15) * T_SEQ +
                                      k0 + ks * 32 + quad * 8);
  };
  loadK(0);        // issued before Q staging: latency hides under stage+barrier
  loadV(0);

  // ---- stage Q tile (16KB) ----
#pragma unroll
  for (int i = 0; i < 2; ++i) {
    int c = tid + 512 * i;                 // 1024 16B-chunks
    int row = c >> 5, c16 = c & 31;
    *(f32x4*)(&sQ[row * 264 + c16 * 8]) =
        *(const f32x4*)(Qb + (size_t)(q0 + row) * 256 + c16 * 8);
  }
  wg_barrier_lds();   // K/V prologue loads stay in flight

  // ---- preload Q A-frags (rows wm*16+l15, both planes, 4 ksteps) ----
  bf16x8 qf[2][4];
  {
    const int row = wm * 16 + l15;
#pragma unroll
    for (int pl = 0; pl < 2; ++pl)
#pragma unroll
      for (int s = 0; s < 4; ++s)
        qf[pl][s] = *(const bf16x8*)(&sQ[row * 264 + pl * 128 + s * 32 + quad * 8]);
  }

  f32x4 O[2][2];
#pragma unroll
  for (int i = 0; i < 2; ++i)
#pragma unroll
    for (int j = 0; j < 2; ++j) O[i][j] = (f32x4){0.f, 0.f, 0.f, 0.f};
  float z[2][4] = {};

  for (int kt = 0; kt < nkt; ++kt) {
    const int k0 = kt << 7;
    const bool needmask = (k0 + 127 > q0 + 1);
    const int buf = kt & 1;

    // ---- QK^T: consume kf (loaded last iteration / prologue) ----
    f32x4 S[2][2];
#pragma unroll
    for (int mat = 0; mat < 2; ++mat) {
      S[mat][0] = (f32x4){0.f, 0.f, 0.f, 0.f};
      S[mat][1] = (f32x4){0.f, 0.f, 0.f, 0.f};
#pragma unroll
      for (int s = 0; s < 4; ++s) {
        S[mat][0] = MFMA16(qf[mat][s], kf[mat][0][s], S[mat][0], 0, 0, 0);
        S[mat][1] = MFMA16(qf[mat][s], kf[mat][1][s], S[mat][1], 0, 0, 0);
      }
    }
    // prefetch next K into the same regs (WAR): hides under exp+barrier+PV
    if (kt + 1 < nkt) loadK(k0 + 128);

    // ---- exp + z partials + write P (bf16) to LDS ----
    const int rowl = wm * 16 + quad * 4;
#pragma unroll
    for (int mat = 0; mat < 2; ++mat)
#pragma unroll
      for (int nt = 0; nt < 2; ++nt) {
        const int keyg = k0 + wk * 32 + nt * 16 + l15;
#pragma unroll
        for (int r = 0; r < 4; ++r) {
          float pv;
          if (needmask) {
            int rowg = q0 + rowl + r;
            pv = (keyg <= rowg + 1) ? __expf(S[mat][nt][r] * SCALE) : 0.f;
          } else {
            pv = __expf(S[mat][nt][r] * SCALE);
          }
          z[mat][r] += pv;
          sP[buf][mat][(rowl + r) * 136 + wk * 32 + nt * 16 + l15] = (__bf16)pv;
        }
      }
    wg_barrier_lds();   // P visible; K prefetch stays in flight

    // ---- PV: O += P @ V (P from LDS, V from rotated regs) ----
#pragma unroll
    for (int ks = 0; ks < 4; ++ks) {
      bf16x8 pf0 = *(const bf16x8*)(&sP[buf][0][(wm * 16 + l15) * 136 + ks * 32 + quad * 8]);
      bf16x8 pf1 = *(const bf16x8*)(&sP[buf][1][(wm * 16 + l15) * 136 + ks * 32 + quad * 8]);
#pragma unroll
      for (int nt = 0; nt < 2; ++nt) {
        O[0][nt] = MFMA16(pf0, vf[nt][ks], O[0][nt], 0, 0, 0);
        O[1][nt] = MFMA16(pf1, vf[nt][ks], O[1][nt], 0, 0, 0);
      }
    }
    // prefetch next V (hides under next iteration's QK phase)
    if (kt + 1 < nkt) loadV(k0 + 128);
    // no trailing barrier: sP is double-buffered
  }

  // ---- Z reduction ----
#pragma unroll
  for (int mat = 0; mat < 2; ++mat)
#pragma unroll
    for (int r = 0; r < 4; ++r)
      zb[mat][wm * 16 + quad * 4 + r][wk * 16 + l15] = z[mat][r];
  __syncthreads();
  if (tid < 64) {
    int mat = tid >> 5, row = tid & 31;
    float s = 0.f;
#pragma unroll
    for (int j = 0; j < 64; ++j) s += zb[mat][row][(j + tid) & 63];  // bank-spread
    zfin[mat][row] = s;
  }
  __syncthreads();

  // ---- epilogue: normalize + closed-form masked tail + pad rows ----
#pragma unroll
  for (int r = 0; r < 4; ++r) {
    const int rowl = wm * 16 + quad * 4 + r;
    const int rowg = q0 + rowl;
    const int nallow = min(rowg + 2, T_SEQ);
    const float nmask = (float)(T_SEQ - nallow);
    const float Z1 = zfin[0][rowl] + nmask;
    const float Z2 = zfin[1][rowl] + nmask;
    const float i1 = 1.f / Z1, i2 = lbd / Z2;
    const float tc = i1 - i2;
    const bool isp = (pad[b * T_SEQ + rowg] == 1);
#pragma unroll
    for (int nt = 0; nt < 2; ++nt) {
      const int col = wk * 32 + nt * 16 + l15;
      const float ct = cumb[(size_t)T_SEQ * HS + col];
      const float cn = cumb[(size_t)nallow * HS + col];
      float val = isp ? (pc * ct)
                      : (O[0][nt][r] * i1 - O[1][nt][r] * i2 + tc * (ct - cn));
      out[((size_t)b * T_SEQ + rowg) * HS + col] = val;
    }
  }
}

// ---------------------------------------------------------------------------
extern "C" void kernel_launch(void* const* d_in, const int* in_sizes, int n_in,
                              void* d_out, int out_size, void* d_ws, size_t ws_size,
                              hipStream_t stream) {
  (void)in_sizes; (void)n_in; (void)out_size; (void)ws_size;
  const float* q   = (const float*)d_in[0];
  const float* k   = (const float*)d_in[1];
  const float* v   = (const float*)d_in[2];
  const int*   pm  = (const int*)d_in[3];
  const float* Wq  = (const float*)d_in[4];
  const float* Wk  = (const float*)d_in[5];
  const float* Wv  = (const float*)d_in[6];
  const float* lq1 = (const float*)d_in[7];
  const float* lk1 = (const float*)d_in[8];
  const float* lq2 = (const float*)d_in[9];
  const float* lk2 = (const float*)d_in[10];
  float* out = (float*)d_out;
  char* ws = (char*)d_ws;

  // workspace layout (bytes)
  float*  lbd  = (float*)ws;                                   // 16
  __bf16* Wp   = (__bf16*)(ws + 16);                           // 40*32*64*8*2 = 1310720
  __bf16* Qp   = (__bf16*)(ws + 16 + 1310720);                 // 8*2048*256*2
  __bf16* Kp   = Qp + (size_t)NB * T_SEQ * 256;
  __bf16* Vp   = Kp + (size_t)NB * T_SEQ * 256;                // 8*2048*128*2
  __bf16* Vt   = Vp + (size_t)NB * T_SEQ * HS;
  float*  cum  = (float*)(Vt + (size_t)NB * T_SEQ * HS);       // 8*2049*128*4
  float*  csum = cum + (size_t)NB * (T_SEQ + 1) * HS;          // 8*16*128*4

  lambda_kernel<<<dim3(1), dim3(128), 0, stream>>>(lq1, lk1, lq2, lk2, lbd);
  pack_w<<<dim3(40), dim3(256), 0, stream>>>(Wq, Wk, Wv, Wp);
  proj_mfma<<<dim3(384), dim3(256), 0, stream>>>(q, k, v, Wp, Qp, Kp, Vp, Vt);
  vcsum_a<<<dim3(128), dim3(128), 0, stream>>>(Vp, csum);
  vcsum_b<<<dim3(128), dim3(128), 0, stream>>>(Vp, csum, cum);
  attn_mfma<<<dim3(512), dim3(512), 0, stream>>>(Qp, Kp, Vt, cum, pm, lbd, out);
}

// Round 7
// 329.755 us; speedup vs baseline: 1.2068x; 1.1248x over previous
//
#include <hip/hip_runtime.h>
#include <math.h>

// ---------------------------------------------------------------------------
// DiffHead, MFMA edition, round 13: attn K-loads through LDS (gld16), not VGPRs.
//   r11/r12 post-mortem arithmetic: avg block = 49us for 8.5 iters = ~14K
//   cycles/iter, invariant across schedules. Cause: K/V loads have VGPR
//   destinations (kf+vf = 96 VGPRs of 104) -> allocator sinks "prefetch" to
//   use sites, issues loads in small batches, each exposing a full L2 round
//   trip. Register loads cannot be deep-queued at this budget.
//   Fix (m97 machinery, proven in proj_mfma below): BK=64, K tile double-
//   buffered in LDS via global_load_lds (zero VGPR cost, deep queue):
//     top __syncthreads (tile ready) -> issue V reg-loads (oldest) ->
//     issue stageK(kt+1) -> QK from LDS -> exp/P -> lgkm-only barrier ->
//     PV (vf wait = counted vmcnt, staging stays in flight) -> __syncthreads.
//   K staged with XOR chunk swizzle (pre-swizzled GLOBAL source, linear LDS
//   dest) so ds_read_b128 frag reads are ~2-way conflict (free, m136).
//   Also: vcsum grid widened 128->512 blocks (64 chunks of 32 rows).
// Math identical: fill=1e-9 => exp(fill*scale)==1.0f -> masked tail
//   closed-form via V prefix sums; padded rows closed form; fixed shift m=0.
// MFMA 16x16x32_bf16 layouts: A/B lane: m/n=lane&15, k=quad*8+j (16B contig);
//   C/D: col=lane&15, row=quad*4+reg.
// ---------------------------------------------------------------------------

#define T_SEQ 2048
#define NB 8
#define CDIM 1024
#define HS 128

constexpr float SCALE = 0.08838834764831845f;   // 128^-0.5

typedef float f32x4 __attribute__((ext_vector_type(4)));
typedef __bf16 bf16x8 __attribute__((ext_vector_type(8)));
typedef unsigned int u32;

#define MFMA16 __builtin_amdgcn_mfma_f32_16x16x32_bf16

__device__ __forceinline__ void gld16(const void* g, void* l) {
  __builtin_amdgcn_global_load_lds(
      (const __attribute__((address_space(1))) u32*)g,
      (__attribute__((address_space(3))) u32*)l, 16, 0, 0);
}

// barrier that makes LDS traffic visible but leaves global/staging loads in flight
__device__ __forceinline__ void wg_barrier_lds() {
  asm volatile("s_waitcnt lgkmcnt(0)" ::: "memory");
  __builtin_amdgcn_s_barrier();
  __builtin_amdgcn_sched_barrier(0);
}

__device__ __forceinline__ bf16x8 cvt8(f32x4 lo, f32x4 hi) {
  bf16x8 r;
  r[0] = (__bf16)lo.x; r[1] = (__bf16)lo.y; r[2] = (__bf16)lo.z; r[3] = (__bf16)lo.w;
  r[4] = (__bf16)hi.x; r[5] = (__bf16)hi.y; r[6] = (__bf16)hi.z; r[7] = (__bf16)hi.w;
  return r;
}

// --------------------------- lambda = exp(lq1.lk1) - exp(lq2.lk2) + 0.8 -----
__global__ __launch_bounds__(128) void lambda_kernel(
    const float* __restrict__ lq1, const float* __restrict__ lk1,
    const float* __restrict__ lq2, const float* __restrict__ lk2,
    float* __restrict__ lbd) {
  __shared__ float r1[128], r2[128];
  int t = threadIdx.x;
  r1[t] = lq1[t] * lk1[t];
  r2[t] = lq2[t] * lk2[t];
  __syncthreads();
  for (int s = 64; s > 0; s >>= 1) {
    if (t < s) { r1[t] += r1[t + s]; r2[t] += r2[t + s]; }
    __syncthreads();
  }
  if (t == 0) *lbd = expf(r1[0]) - expf(r2[0]) + 0.8f;
}

// --------------------------- pack W: lane-contiguous B-frag chunks ----------
// Wp chunk (ntile 0..39, ks 0..31): 1KB = 64 lanes x 16B; lane (quad,l15):
//   n = ntile*16 + l15, k = ks*32 + quad*8 .. +7.  ntile: q 0-15, k 16-31, v 32-39.
__global__ __launch_bounds__(256) void pack_w(
    const float* __restrict__ Wq, const float* __restrict__ Wk,
    const float* __restrict__ Wv, __bf16* __restrict__ Wp) {
  int nt = blockIdx.x;  // 0..39
  const float* W; int colbase, N;
  if (nt < 16)      { W = Wq; colbase = nt * 16;        N = 256; }
  else if (nt < 32) { W = Wk; colbase = (nt - 16) * 16; N = 256; }
  else              { W = Wv; colbase = (nt - 32) * 16; N = 128; }
  int tid = threadIdx.x;
#pragma unroll
  for (int i = 0; i < 8; ++i) {
    int u = tid + 256 * i;            // 2048 = 32 ks * 64 lanes
    int ks = u >> 6, lane = u & 63;
    int l15 = lane & 15, quad = lane >> 4;
    bf16x8 pk;
#pragma unroll
    for (int j = 0; j < 8; ++j)
      pk[j] = (__bf16)W[(size_t)(ks * 32 + quad * 8 + j) * N + colbase + l15];
    *(bf16x8*)(Wp + ((size_t)(nt * 32 + ks) * 64 + lane) * 8) = pk;
  }
}

// --------------------------- projection GEMM body (templated on NT) ---------
// NT = n-tiles of 16 (16 for q/k, 8 for v); NTG = n-tile offset into Wp.
// Block = 128 rows x all N. BK=32 double-buffered global_load_lds staging.
template<int NT, int NTG>
__device__ __forceinline__ void proj_body(
    const float* __restrict__ Ablk, const __bf16* __restrict__ Wp,
    __bf16* __restrict__ outp, __bf16* __restrict__ Vt,
    int rows0, char* smem) {
  float*  sA = (float*)smem;                    // 2 x 4096 floats (32KB)
  __bf16* sB = (__bf16*)(smem + 32768);         // 2 x 8192 bf16  (32KB)
  const int tid = threadIdx.x;
  const int lane = tid & 63, wave = tid >> 6;
  const int l15 = lane & 15, quad = lane >> 4;
  const int arow = lane >> 3;                   // A-staging row-within-8
  const int ac16 = (lane & 7) ^ arow;           // XOR swizzle (row&7)

  f32x4 acc0[NT], acc1[NT];
#pragma unroll
  for (int j = 0; j < NT; ++j) {
    acc0[j] = (f32x4){0.f, 0.f, 0.f, 0.f};
    acc1[j] = (f32x4){0.f, 0.f, 0.f, 0.f};
  }

  auto stage_ks = [&](int ks, int buf) {
    const float* gA = Ablk + ks * 32;
    float* lA = sA + buf * 4096;
#pragma unroll
    for (int i = 0; i < 4; ++i) {
      int li = wave * 4 + i;                     // 16 loads, 8 rows each
      gld16(gA + (size_t)(li * 8 + arow) * CDIM + ac16 * 4, lA + li * 256);
    }
    __bf16* lB = sB + buf * 8192;
#pragma unroll
    for (int i = 0; i < 4; ++i) {
      int ntl = wave * 4 + i;                    // one 1KB chunk per n-tile
      if (ntl < NT)
        gld16(Wp + ((size_t)((NTG + ntl) * 32 + ks) * 64 + lane) * 8,
              lB + ntl * 512);
    }
  };

  stage_ks(0, 0);
  for (int ks = 0; ks < 32; ++ks) {
    const int buf = ks & 1;
    __syncthreads();
    // A frags (un-swizzle: chunk c of row r lives at LDS pos c^(r&7))
    const float* lA = sA + buf * 4096;
    int r0 = wave * 32 + l15;
    f32x4 lo0 = *(const f32x4*)(lA + r0 * 32 + (((quad * 2)     ^ (l15 & 7)) * 4));
    f32x4 hi0 = *(const f32x4*)(lA + r0 * 32 + (((quad * 2 + 1) ^ (l15 & 7)) * 4));
    bf16x8 af0 = cvt8(lo0, hi0);
    int r1 = r0 + 16;
    f32x4 lo1 = *(const f32x4*)(lA + r1 * 32 + (((quad * 2)     ^ (l15 & 7)) * 4));
    f32x4 hi1 = *(const f32x4*)(lA + r1 * 32 + (((quad * 2 + 1) ^ (l15 & 7)) * 4));
    bf16x8 af1 = cvt8(lo1, hi1);
    if (ks < 31) stage_ks(ks + 1, buf ^ 1);      // prefetch overlaps MFMA
    const __bf16* lB = sB + buf * 8192;
#pragma unroll
    for (int nt = 0; nt < NT; ++nt) {            // constexpr trip count!
      bf16x8 bf = *(const bf16x8*)(lB + nt * 512 + lane * 8);
      acc0[nt] = MFMA16(af0, bf, acc0[nt], 0, 0, 0);
      acc1[nt] = MFMA16(af1, bf, acc1[nt], 0, 0, 0);
    }
  }

  // ---- epilogue: C through LDS tile -> coalesced 16B stores ----
  __syncthreads();
  __bf16* tile = (__bf16*)smem;                  // [128][136] bf16 (34.8KB)
  constexpr int N = NT * 16;
#pragma unroll
  for (int half = 0; half < (NT >> 3); ++half) {
#pragma unroll
    for (int ntl = 0; ntl < 8; ++ntl) {
      f32x4 a0 = acc0[half * 8 + ntl];
      f32x4 a1 = acc1[half * 8 + ntl];
#pragma unroll
      for (int r = 0; r < 4; ++r) {
        tile[(wave * 32 + quad * 4 + r) * 136 + ntl * 16 + l15] = (__bf16)a0[r];
        tile[(wave * 32 + 16 + quad * 4 + r) * 136 + ntl * 16 + l15] = (__bf16)a1[r];
      }
    }
    __syncthreads();
#pragma unroll
    for (int i = 0; i < 8; ++i) {
      int u = tid + 256 * i;                     // 2048 chunks: 128 rows x 16x16B
      int row = u >> 4, c8 = u & 15;
      bf16x8 val = *(const bf16x8*)(tile + row * 136 + c8 * 8);
      *(bf16x8*)(outp + (size_t)(rows0 + row) * N + half * 128 + c8 * 8) = val;
    }
    if constexpr (NT == 8) {                     // v: also Vt[b][c][t] via transpose
      int b = rows0 >> 11, t0 = rows0 & 2047;
#pragma unroll
      for (int i = 0; i < 8; ++i) {
        int u = tid + 256 * i;                   // 2048 = 16 tc x 128 c
        int tc = u & 15, c = u >> 4;
        bf16x8 pk;
#pragma unroll
        for (int j = 0; j < 8; ++j) pk[j] = tile[(tc * 8 + j) * 136 + c];
        *(bf16x8*)(Vt + ((size_t)(b * 128 + c)) * T_SEQ + t0 + tc * 8) = pk;
      }
    }
    __syncthreads();
  }
}

// 384 blocks x 256 thr. Blocks 0..127: q->Q(N=256); 128..255: k->K; 256..383: v->V(+Vt).
__global__ __launch_bounds__(256, 2) void proj_mfma(
    const float* __restrict__ qin, const float* __restrict__ kin,
    const float* __restrict__ vin, const __bf16* __restrict__ Wp,
    __bf16* __restrict__ Qo, __bf16* __restrict__ Ko,
    __bf16* __restrict__ Vo, __bf16* __restrict__ Vt) {
  __shared__ char smem[65536];
  const int blk = blockIdx.x;
  const int rows0 = (blk & 127) * 128;
  if (blk < 128)
    proj_body<16, 0>(qin + (size_t)rows0 * CDIM, Wp, Qo, nullptr, rows0, smem);
  else if (blk < 256)
    proj_body<16, 16>(kin + (size_t)rows0 * CDIM, Wp, Ko, nullptr, rows0, smem);
  else
    proj_body<8, 32>(vin + (size_t)rows0 * CDIM, Wp, Vo, Vt, rows0, smem);
}

// --------------------------- V prefix sums (bf16 in, fp32 out) --------------
// 64 chunks of 32 rows per batch: 512 blocks (was 128 -> 0.5 waves/CU).
#define VCH 64
#define VCS 32
__global__ __launch_bounds__(128) void vcsum_a(const __bf16* __restrict__ V,
                                               float* __restrict__ csum) {
  int blk = blockIdx.x; int b = blk >> 6, ch = blk & 63;
  int c = threadIdx.x;
  const __bf16* vp = V + ((size_t)b * T_SEQ + ch * VCS) * HS + c;
  float s = 0.f;
#pragma unroll 4
  for (int t = 0; t < VCS; ++t) s += (float)vp[(size_t)t * HS];
  csum[(size_t)blk * HS + c] = s;
}

__global__ __launch_bounds__(128) void vcsum_b(const __bf16* __restrict__ V,
                                               const float* __restrict__ csum,
                                               float* __restrict__ cum) {
  int blk = blockIdx.x; int b = blk >> 6, ch = blk & 63;
  int c = threadIdx.x;
  float run = 0.f;
  for (int j = 0; j < ch; ++j) run += csum[(size_t)(b * VCH + j) * HS + c];
  const __bf16* vp = V + ((size_t)b * T_SEQ + ch * VCS) * HS + c;
  float* cp = cum + ((size_t)b * (T_SEQ + 1) + ch * VCS) * HS + c;
  if (ch == 0) cp[0] = 0.f;
#pragma unroll 4
  for (int t = 0; t < VCS; ++t) {
    run += (float)vp[(size_t)t * HS];
    cp[(size_t)(t + 1) * HS] = run;
  }
}

// --------------------------- attention (bf16 MFMA, flash-style) -------------
// 512 blocks x 512 thr (8 waves: wm = wave>>2 m-split, wk = wave&3 key-split).
// One 32-row q-tile per block; ti = 63-(p>>3) (LPT); b = p&7 (XCD locality).
// BK=64: K tile double-buffered in LDS via global_load_lds (swizzled global
// source, linear LDS dest); V frags via register loads issued oldest-first so
// PV's vmcnt wait leaves the K staging in flight.
__global__ __launch_bounds__(512, 2) void attn_mfma(
    const __bf16* __restrict__ Q, const __bf16* __restrict__ K,
    const __bf16* __restrict__ Vt, const float* __restrict__ cum,
    const int* __restrict__ pad, const float* __restrict__ lbdp,
    float* __restrict__ out) {
  __shared__ __bf16 sQ[32 * 264];         // 16.9KB
  __shared__ __bf16 sK[2][64 * 256];      // 64KB  (swizzled chunks)
  __shared__ __bf16 sP[2][2][32 * 72];    // 18.4KB (pad 72: 2-way free)
  __shared__ float zb[2][32][64];         // 16.4KB
  __shared__ float zfin[2][32];

  const int tid = threadIdx.x;
  const int lane = tid & 63, wave = tid >> 6;
  const int wm = wave >> 2, wk = wave & 3;
  const int l15 = lane & 15, quad = lane >> 4;

  const int p = blockIdx.x;
  const int b = p & 7;
  const int ti = 63 - (p >> 3);              // LPT order: big tiles first
  const int q0 = ti * 32;
  const float lbd = *lbdp;
  const __bf16* Qb = Q + (size_t)b * T_SEQ * 256;
  const __bf16* Kb = K + (size_t)b * T_SEQ * 256;
  const __bf16* Vtb = Vt + (size_t)b * HS * T_SEQ;
  const float* cumb = cum + (size_t)b * (T_SEQ + 1) * HS;
  const float pc = (1.f - lbd) * (1.f / (float)T_SEQ);

  const int lastkey = q0 + 32;             // max allowed key (row q0+31, +1 lookahead)
  const int nkt = (min(lastkey, T_SEQ - 1) >> 6) + 1;

  // stage K tile [k0,k0+64) into sK[sbuf]: 2048 16B chunks, 4 gld16/thread.
  // LDS slot (row, c) holds global chunk (c&24)|((c^row)&7)  (XOR involution).
  auto stageK = [&](int k0, int sbuf) {
#pragma unroll
    for (int i = 0; i < 4; ++i) {
      int u = i * 512 + tid;
      int row = u >> 5, c = u & 31;
      int cg = (c & 24) | ((c ^ row) & 7);
      gld16(Kb + (size_t)(k0 + row) * 256 + cg * 8,
            &sK[sbuf][(size_t)(i * 512 + wave * 64) * 8]);
    }
  };

  stageK(0, 0);                            // oldest: overlaps Q staging
  // ---- stage Q tile (16KB, register path) ----
#pragma unroll
  for (int i = 0; i < 2; ++i) {
    int c = tid + 512 * i;                 // 1024 16B-chunks
    int row = c >> 5, c16 = c & 31;
    *(f32x4*)(&sQ[row * 264 + c16 * 8]) =
        *(const f32x4*)(Qb + (size_t)(q0 + row) * 256 + c16 * 8);
  }
  __syncthreads();                         // Q + K tile 0 ready

  // ---- preload Q A-frags (rows wm*16+l15, both planes, 4 ksteps) ----
  bf16x8 qf[2][4];
  {
    const int row = wm * 16 + l15;
#pragma unroll
    for (int pl = 0; pl < 2; ++pl)
#pragma unroll
      for (int s = 0; s < 4; ++s)
        qf[pl][s] = *(const bf16x8*)(&sQ[row * 264 + pl * 128 + s * 32 + quad * 8]);
  }

  f32x4 O[2][2];
#pragma unroll
  for (int i = 0; i < 2; ++i)
#pragma unroll
    for (int j = 0; j < 2; ++j) O[i][j] = (f32x4){0.f, 0.f, 0.f, 0.f};
  float z[2][4] = {};

  const int kr = wk * 16 + l15;            // this wave's key row within tile

  for (int kt = 0; kt < nkt; ++kt) {
    const int k0 = kt << 6;
    const int buf = kt & 1;
    const bool needmask = (k0 + 63 > q0 + 1);

    // V frags for THIS tile: issued first (oldest VMEM of the iteration)
    bf16x8 vf[2][2];
#pragma unroll
    for (int nt = 0; nt < 2; ++nt)
#pragma unroll
      for (int ks = 0; ks < 2; ++ks)
        vf[nt][ks] = *(const bf16x8*)(Vtb + (size_t)(wk * 32 + nt * 16 + l15) * T_SEQ +
                                      k0 + ks * 32 + quad * 8);
    // stage NEXT K tile (younger than vf: PV's vf-wait leaves it in flight)
    if (kt + 1 < nkt) stageK(k0 + 64, buf ^ 1);

    // ---- QK^T from LDS (un-swizzle on read) ----
    f32x4 S[2];
#pragma unroll
    for (int mat = 0; mat < 2; ++mat) {
      S[mat] = (f32x4){0.f, 0.f, 0.f, 0.f};
#pragma unroll
      for (int s = 0; s < 4; ++s) {
        int cd = mat * 16 + s * 4 + quad;
        int slot = (cd & 24) | ((cd ^ kr) & 7);
        bf16x8 kfrag = *(const bf16x8*)(&sK[buf][(size_t)kr * 256 + slot * 8]);
        S[mat] = MFMA16(qf[mat][s], kfrag, S[mat], 0, 0, 0);
      }
    }

    // ---- exp + z partials + write P (bf16) to LDS ----
    const int rowl = wm * 16 + quad * 4;
    const int keyg = k0 + kr;
#pragma unroll
    for (int mat = 0; mat < 2; ++mat)
#pragma unroll
      for (int r = 0; r < 4; ++r) {
        float pv;
        if (needmask) {
          int rowg = q0 + rowl + r;
          pv = (keyg <= rowg + 1) ? __expf(S[mat][r] * SCALE) : 0.f;
        } else {
          pv = __expf(S[mat][r] * SCALE);
        }
        z[mat][r] += pv;
        sP[buf][mat][(rowl + r) * 72 + kr] = (__bf16)pv;
      }
    wg_barrier_lds();   // P visible; K staging stays in flight

    // ---- PV: O += P @ V (P from LDS, V from regs; vmcnt(4) wait on vf) ----
#pragma unroll
    for (int ks = 0; ks < 2; ++ks) {
      bf16x8 pf0 = *(const bf16x8*)(&sP[buf][0][(wm * 16 + l15) * 72 + ks * 32 + quad * 8]);
      bf16x8 pf1 = *(const bf16x8*)(&sP[buf][1][(wm * 16 + l15) * 72 + ks * 32 + quad * 8]);
#pragma unroll
      for (int nt = 0; nt < 2; ++nt) {
        O[0][nt] = MFMA16(pf0, vf[nt][ks], O[0][nt], 0, 0, 0);
        O[1][nt] = MFMA16(pf1, vf[nt][ks], O[1][nt], 0, 0, 0);
      }
    }
    __syncthreads();    // next tile ready (staging had ~full iteration)
  }

  // ---- Z reduction ----
#pragma unroll
  for (int mat = 0; mat < 2; ++mat)
#pragma unroll
    for (int r = 0; r < 4; ++r)
      zb[mat][wm * 16 + quad * 4 + r][wk * 16 + l15] = z[mat][r];
  __syncthreads();
  if (tid < 64) {
    int mat = tid >> 5, row = tid & 31;
    float s = 0.f;
#pragma unroll
    for (int j = 0; j < 64; ++j) s += zb[mat][row][(j + tid) & 63];  // bank-spread
    zfin[mat][row] = s;
  }
  __syncthreads();

  // ---- epilogue: normalize + closed-form masked tail + pad rows ----
#pragma unroll
  for (int r = 0; r < 4; ++r) {
    const int rowl = wm * 16 + quad * 4 + r;
    const int rowg = q0 + rowl;
    const int nallow = min(rowg + 2, T_SEQ);
    const float nmask = (float)(T_SEQ - nallow);
    const float Z1 = zfin[0][rowl] + nmask;
    const float Z2 = zfin[1][rowl] + nmask;
    const float i1 = 1.f / Z1, i2 = lbd / Z2;
    const float tc = i1 - i2;
    const bool isp = (pad[b * T_SEQ + rowg] == 1);
#pragma unroll
    for (int nt = 0; nt < 2; ++nt) {
      const int col = wk * 32 + nt * 16 + l15;
      const float ct = cumb[(size_t)T_SEQ * HS + col];
      const float cn = cumb[(size_t)nallow * HS + col];
      float val = isp ? (pc * ct)
                      : (O[0][nt][r] * i1 - O[1][nt][r] * i2 + tc * (ct - cn));
      out[((size_t)b * T_SEQ + rowg) * HS + col] = val;
    }
  }
}

// ---------------------------------------------------------------------------
extern "C" void kernel_launch(void* const* d_in, const int* in_sizes, int n_in,
                              void* d_out, int out_size, void* d_ws, size_t ws_size,
                              hipStream_t stream) {
  (void)in_sizes; (void)n_in; (void)out_size; (void)ws_size;
  const float* q   = (const float*)d_in[0];
  const float* k   = (const float*)d_in[1];
  const float* v   = (const float*)d_in[2];
  const int*   pm  = (const int*)d_in[3];
  const float* Wq  = (const float*)d_in[4];
  const float* Wk  = (const float*)d_in[5];
  const float* Wv  = (const float*)d_in[6];
  const float* lq1 = (const float*)d_in[7];
  const float* lk1 = (const float*)d_in[8];
  const float* lq2 = (const float*)d_in[9];
  const float* lk2 = (const float*)d_in[10];
  float* out = (float*)d_out;
  char* ws = (char*)d_ws;

  // workspace layout (bytes)
  float*  lbd  = (float*)ws;                                   // 16
  __bf16* Wp   = (__bf16*)(ws + 16);                           // 40*32*64*8*2 = 1310720
  __bf16* Qp   = (__bf16*)(ws + 16 + 1310720);                 // 8*2048*256*2
  __bf16* Kp   = Qp + (size_t)NB * T_SEQ * 256;
  __bf16* Vp   = Kp + (size_t)NB * T_SEQ * 256;                // 8*2048*128*2
  __bf16* Vt   = Vp + (size_t)NB * T_SEQ * HS;
  float*  cum  = (float*)(Vt + (size_t)NB * T_SEQ * HS);       // 8*2049*128*4
  float*  csum = cum + (size_t)NB * (T_SEQ + 1) * HS;          // 8*64*128*4

  lambda_kernel<<<dim3(1), dim3(128), 0, stream>>>(lq1, lk1, lq2, lk2, lbd);
  pack_w<<<dim3(40), dim3(256), 0, stream>>>(Wq, Wk, Wv, Wp);
  proj_mfma<<<dim3(384), dim3(256), 0, stream>>>(q, k, v, Wp, Qp, Kp, Vp, Vt);
  vcsum_a<<<dim3(512), dim3(128), 0, stream>>>(Vp, csum);
  vcsum_b<<<dim3(512), dim3(128), 0, stream>>>(Vp, csum, cum);
  attn_mfma<<<dim3(512), dim3(512), 0, stream>>>(Qp, Kp, Vt, cum, pm, lbd, out);
}

// Round 8
// 326.495 us; speedup vs baseline: 1.2189x; 1.0100x over previous
//
#include <hip/hip_runtime.h>
#include <math.h>

// ---------------------------------------------------------------------------
// DiffHead, MFMA edition, round 14: fix proj_mfma grid imbalance.
//   r13 counters: proj 92us, FETCH 103MB, 1.39TB/s (18% HBM), Occ 13.9%.
//   Compulsory traffic floor ~31us -> we're 3x off, not BW-bound. Cause:
//   384 blocks at 64KB LDS = 2 blocks/CU capacity -> 128 CUs get 2 blocks,
//   128 get 1; wall = 2-block CUs (2 x 45us ~= 92 measured), half the chip
//   idles the second half.
//   Fix: 768 blocks of 64 rows (2 waves, 128 thr), LDS 48KB -> exactly
//   3 blocks/CU (144KB); in-order dispatch gives each CU one q, one k, one
//   v block -> uniform 192 rows/CU (vs 256 on critical CUs). 3 staggered
//   blocks also fill each other's staging-latency gaps. Per-wave code
//   unchanged; only wave-count constants + epilogue chunk loops rescaled.
//   attn unchanged from r13 (it left the top-5: LDS-staging fix confirmed).
// Math identical: fill=1e-9 => exp(fill*scale)==1.0f -> masked tail
//   closed-form via V prefix sums; padded rows closed form; fixed shift m=0.
// MFMA 16x16x32_bf16 layouts: A/B lane: m/n=lane&15, k=quad*8+j (16B contig);
//   C/D: col=lane&15, row=quad*4+reg.
// ---------------------------------------------------------------------------

#define T_SEQ 2048
#define NB 8
#define CDIM 1024
#define HS 128

constexpr float SCALE = 0.08838834764831845f;   // 128^-0.5

typedef float f32x4 __attribute__((ext_vector_type(4)));
typedef __bf16 bf16x8 __attribute__((ext_vector_type(8)));
typedef unsigned int u32;

#define MFMA16 __builtin_amdgcn_mfma_f32_16x16x32_bf16

__device__ __forceinline__ void gld16(const void* g, void* l) {
  __builtin_amdgcn_global_load_lds(
      (const __attribute__((address_space(1))) u32*)g,
      (__attribute__((address_space(3))) u32*)l, 16, 0, 0);
}

// barrier that makes LDS traffic visible but leaves global/staging loads in flight
__device__ __forceinline__ void wg_barrier_lds() {
  asm volatile("s_waitcnt lgkmcnt(0)" ::: "memory");
  __builtin_amdgcn_s_barrier();
  __builtin_amdgcn_sched_barrier(0);
}

__device__ __forceinline__ bf16x8 cvt8(f32x4 lo, f32x4 hi) {
  bf16x8 r;
  r[0] = (__bf16)lo.x; r[1] = (__bf16)lo.y; r[2] = (__bf16)lo.z; r[3] = (__bf16)lo.w;
  r[4] = (__bf16)hi.x; r[5] = (__bf16)hi.y; r[6] = (__bf16)hi.z; r[7] = (__bf16)hi.w;
  return r;
}

// --------------------------- lambda = exp(lq1.lk1) - exp(lq2.lk2) + 0.8 -----
__global__ __launch_bounds__(128) void lambda_kernel(
    const float* __restrict__ lq1, const float* __restrict__ lk1,
    const float* __restrict__ lq2, const float* __restrict__ lk2,
    float* __restrict__ lbd) {
  __shared__ float r1[128], r2[128];
  int t = threadIdx.x;
  r1[t] = lq1[t] * lk1[t];
  r2[t] = lq2[t] * lk2[t];
  __syncthreads();
  for (int s = 64; s > 0; s >>= 1) {
    if (t < s) { r1[t] += r1[t + s]; r2[t] += r2[t + s]; }
    __syncthreads();
  }
  if (t == 0) *lbd = expf(r1[0]) - expf(r2[0]) + 0.8f;
}

// --------------------------- pack W: lane-contiguous B-frag chunks ----------
// Wp chunk (ntile 0..39, ks 0..31): 1KB = 64 lanes x 16B; lane (quad,l15):
//   n = ntile*16 + l15, k = ks*32 + quad*8 .. +7.  ntile: q 0-15, k 16-31, v 32-39.
__global__ __launch_bounds__(256) void pack_w(
    const float* __restrict__ Wq, const float* __restrict__ Wk,
    const float* __restrict__ Wv, __bf16* __restrict__ Wp) {
  int nt = blockIdx.x;  // 0..39
  const float* W; int colbase, N;
  if (nt < 16)      { W = Wq; colbase = nt * 16;        N = 256; }
  else if (nt < 32) { W = Wk; colbase = (nt - 16) * 16; N = 256; }
  else              { W = Wv; colbase = (nt - 32) * 16; N = 128; }
  int tid = threadIdx.x;
#pragma unroll
  for (int i = 0; i < 8; ++i) {
    int u = tid + 256 * i;            // 2048 = 32 ks * 64 lanes
    int ks = u >> 6, lane = u & 63;
    int l15 = lane & 15, quad = lane >> 4;
    bf16x8 pk;
#pragma unroll
    for (int j = 0; j < 8; ++j)
      pk[j] = (__bf16)W[(size_t)(ks * 32 + quad * 8 + j) * N + colbase + l15];
    *(bf16x8*)(Wp + ((size_t)(nt * 32 + ks) * 64 + lane) * 8) = pk;
  }
}

// --------------------------- projection GEMM body (templated on NT) ---------
// NT = n-tiles of 16 (16 for q/k, 8 for v); NTG = n-tile offset into Wp.
// Block = 64 rows x all N, 128 threads (2 waves). BK=32 double-buffered
// global_load_lds staging; 48KB LDS -> 3 blocks/CU.
template<int NT, int NTG>
__device__ __forceinline__ void proj_body(
    const float* __restrict__ Ablk, const __bf16* __restrict__ Wp,
    __bf16* __restrict__ outp, __bf16* __restrict__ Vt,
    int rows0, char* smem) {
  float*  sA = (float*)smem;                    // 2 x 2048 floats (16KB)
  __bf16* sB = (__bf16*)(smem + 16384);         // 2 x 8192 bf16  (32KB)
  const int tid = threadIdx.x;
  const int lane = tid & 63, wave = tid >> 6;   // 2 waves
  const int l15 = lane & 15, quad = lane >> 4;
  const int arow = lane >> 3;                   // A-staging row-within-8
  const int ac16 = (lane & 7) ^ arow;           // XOR swizzle (row&7)

  f32x4 acc0[NT], acc1[NT];
#pragma unroll
  for (int j = 0; j < NT; ++j) {
    acc0[j] = (f32x4){0.f, 0.f, 0.f, 0.f};
    acc1[j] = (f32x4){0.f, 0.f, 0.f, 0.f};
  }

  auto stage_ks = [&](int ks, int buf) {
    const float* gA = Ablk + ks * 32;
    float* lA = sA + buf * 2048;
#pragma unroll
    for (int i = 0; i < 4; ++i) {
      int li = wave * 4 + i;                     // 8 chunks, 8 rows each
      gld16(gA + (size_t)(li * 8 + arow) * CDIM + ac16 * 4, lA + li * 256);
    }
    __bf16* lB = sB + buf * 8192;
#pragma unroll
    for (int i = 0; i < 8; ++i) {
      int ntl = wave * 8 + i;                    // one 1KB chunk per n-tile
      if (ntl < NT)
        gld16(Wp + ((size_t)((NTG + ntl) * 32 + ks) * 64 + lane) * 8,
              lB + ntl * 512);
    }
  };

  stage_ks(0, 0);
  for (int ks = 0; ks < 32; ++ks) {
    const int buf = ks & 1;
    __syncthreads();
    // A frags (un-swizzle: chunk c of row r lives at LDS pos c^(r&7))
    const float* lA = sA + buf * 2048;
    int r0 = wave * 32 + l15;
    f32x4 lo0 = *(const f32x4*)(lA + r0 * 32 + (((quad * 2)     ^ (l15 & 7)) * 4));
    f32x4 hi0 = *(const f32x4*)(lA + r0 * 32 + (((quad * 2 + 1) ^ (l15 & 7)) * 4));
    bf16x8 af0 = cvt8(lo0, hi0);
    int r1 = r0 + 16;
    f32x4 lo1 = *(const f32x4*)(lA + r1 * 32 + (((quad * 2)     ^ (l15 & 7)) * 4));
    f32x4 hi1 = *(const f32x4*)(lA + r1 * 32 + (((quad * 2 + 1) ^ (l15 & 7)) * 4));
    bf16x8 af1 = cvt8(lo1, hi1);
    if (ks < 31) stage_ks(ks + 1, buf ^ 1);      // prefetch overlaps MFMA
    const __bf16* lB = sB + buf * 8192;
#pragma unroll
    for (int nt = 0; nt < NT; ++nt) {            // constexpr trip count!
      bf16x8 bf = *(const bf16x8*)(lB + nt * 512 + lane * 8);
      acc0[nt] = MFMA16(af0, bf, acc0[nt], 0, 0, 0);
      acc1[nt] = MFMA16(af1, bf, acc1[nt], 0, 0, 0);
    }
  }

  // ---- epilogue: C through LDS tile -> coalesced 16B stores ----
  __syncthreads();
  __bf16* tile = (__bf16*)smem;                  // [64][136] bf16 (17.4KB)
  constexpr int N = NT * 16;
#pragma unroll
  for (int half = 0; half < (NT >> 3); ++half) {
#pragma unroll
    for (int ntl = 0; ntl < 8; ++ntl) {
      f32x4 a0 = acc0[half * 8 + ntl];
      f32x4 a1 = acc1[half * 8 + ntl];
#pragma unroll
      for (int r = 0; r < 4; ++r) {
        tile[(wave * 32 + quad * 4 + r) * 136 + ntl * 16 + l15] = (__bf16)a0[r];
        tile[(wave * 32 + 16 + quad * 4 + r) * 136 + ntl * 16 + l15] = (__bf16)a1[r];
      }
    }
    __syncthreads();
#pragma unroll
    for (int i = 0; i < 8; ++i) {
      int u = tid + 128 * i;                     // 1024 chunks: 64 rows x 16x16B
      int row = u >> 4, c8 = u & 15;
      bf16x8 val = *(const bf16x8*)(tile + row * 136 + c8 * 8);
      *(bf16x8*)(outp + (size_t)(rows0 + row) * N + half * 128 + c8 * 8) = val;
    }
    if constexpr (NT == 8) {                     // v: also Vt[b][c][t] via transpose
      int b = rows0 >> 11, t0 = rows0 & 2047;
#pragma unroll
      for (int i = 0; i < 8; ++i) {
        int u = tid + 128 * i;                   // 1024 = 8 tc x 128 c
        int tc = u & 7, c = u >> 3;
        bf16x8 pk;
#pragma unroll
        for (int j = 0; j < 8; ++j) pk[j] = tile[(tc * 8 + j) * 136 + c];
        *(bf16x8*)(Vt + ((size_t)(b * 128 + c)) * T_SEQ + t0 + tc * 8) = pk;
      }
    }
    __syncthreads();
  }
}

// 768 blocks x 128 thr (3/CU uniform). 0..255: q->Q(N=256); 256..511: k->K;
// 512..767: v->V(+Vt). In-order dispatch gives each CU ~one of each type.
__global__ __launch_bounds__(128, 2) void proj_mfma(
    const float* __restrict__ qin, const float* __restrict__ kin,
    const float* __restrict__ vin, const __bf16* __restrict__ Wp,
    __bf16* __restrict__ Qo, __bf16* __restrict__ Ko,
    __bf16* __restrict__ Vo, __bf16* __restrict__ Vt) {
  __shared__ char smem[49152];
  const int blk = blockIdx.x;
  const int rows0 = (blk & 255) * 64;
  if (blk < 256)
    proj_body<16, 0>(qin + (size_t)rows0 * CDIM, Wp, Qo, nullptr, rows0, smem);
  else if (blk < 512)
    proj_body<16, 16>(kin + (size_t)rows0 * CDIM, Wp, Ko, nullptr, rows0, smem);
  else
    proj_body<8, 32>(vin + (size_t)rows0 * CDIM, Wp, Vo, Vt, rows0, smem);
}

// --------------------------- V prefix sums (bf16 in, fp32 out) --------------
// 64 chunks of 32 rows per batch: 512 blocks.
#define VCH 64
#define VCS 32
__global__ __launch_bounds__(128) void vcsum_a(const __bf16* __restrict__ V,
                                               float* __restrict__ csum) {
  int blk = blockIdx.x; int b = blk >> 6, ch = blk & 63;
  int c = threadIdx.x;
  const __bf16* vp = V + ((size_t)b * T_SEQ + ch * VCS) * HS + c;
  float s = 0.f;
#pragma unroll 4
  for (int t = 0; t < VCS; ++t) s += (float)vp[(size_t)t * HS];
  csum[(size_t)blk * HS + c] = s;
}

__global__ __launch_bounds__(128) void vcsum_b(const __bf16* __restrict__ V,
                                               const float* __restrict__ csum,
                                               float* __restrict__ cum) {
  int blk = blockIdx.x; int b = blk >> 6, ch = blk & 63;
  int c = threadIdx.x;
  float run = 0.f;
  for (int j = 0; j < ch; ++j) run += csum[(size_t)(b * VCH + j) * HS + c];
  const __bf16* vp = V + ((size_t)b * T_SEQ + ch * VCS) * HS + c;
  float* cp = cum + ((size_t)b * (T_SEQ + 1) + ch * VCS) * HS + c;
  if (ch == 0) cp[0] = 0.f;
#pragma unroll 4
  for (int t = 0; t < VCS; ++t) {
    run += (float)vp[(size_t)t * HS];
    cp[(size_t)(t + 1) * HS] = run;
  }
}

// --------------------------- attention (bf16 MFMA, flash-style) -------------
// 512 blocks x 512 thr (8 waves: wm = wave>>2 m-split, wk = wave&3 key-split).
// One 32-row q-tile per block; ti = 63-(p>>3) (LPT); b = p&7 (XCD locality).
// BK=64: K tile double-buffered in LDS via global_load_lds (swizzled global
// source, linear LDS dest); V frags via register loads issued oldest-first so
// PV's vmcnt wait leaves the K staging in flight.
__global__ __launch_bounds__(512, 2) void attn_mfma(
    const __bf16* __restrict__ Q, const __bf16* __restrict__ K,
    const __bf16* __restrict__ Vt, const float* __restrict__ cum,
    const int* __restrict__ pad, const float* __restrict__ lbdp,
    float* __restrict__ out) {
  __shared__ __bf16 sQ[32 * 264];         // 16.9KB
  __shared__ __bf16 sK[2][64 * 256];      // 64KB  (swizzled chunks)
  __shared__ __bf16 sP[2][2][32 * 72];    // 18.4KB (pad 72: 2-way free)
  __shared__ float zb[2][32][64];         // 16.4KB
  __shared__ float zfin[2][32];

  const int tid = threadIdx.x;
  const int lane = tid & 63, wave = tid >> 6;
  const int wm = wave >> 2, wk = wave & 3;
  const int l15 = lane & 15, quad = lane >> 4;

  const int p = blockIdx.x;
  const int b = p & 7;
  const int ti = 63 - (p >> 3);              // LPT order: big tiles first
  const int q0 = ti * 32;
  const float lbd = *lbdp;
  const __bf16* Qb = Q + (size_t)b * T_SEQ * 256;
  const __bf16* Kb = K + (size_t)b * T_SEQ * 256;
  const __bf16* Vtb = Vt + (size_t)b * HS * T_SEQ;
  const float* cumb = cum + (size_t)b * (T_SEQ + 1) * HS;
  const float pc = (1.f - lbd) * (1.f / (float)T_SEQ);

  const int lastkey = q0 + 32;             // max allowed key (row q0+31, +1 lookahead)
  const int nkt = (min(lastkey, T_SEQ - 1) >> 6) + 1;

  // stage K tile [k0,k0+64) into sK[sbuf]: 2048 16B chunks, 4 gld16/thread.
  // LDS slot (row, c) holds global chunk (c&24)|((c^row)&7)  (XOR involution).
  auto stageK = [&](int k0, int sbuf) {
#pragma unroll
    for (int i = 0; i < 4; ++i) {
      int u = i * 512 + tid;
      int row = u >> 5, c = u & 31;
      int cg = (c & 24) | ((c ^ row) & 7);
      gld16(Kb + (size_t)(k0 + row) * 256 + cg * 8,
            &sK[sbuf][(size_t)(i * 512 + wave * 64) * 8]);
    }
  };

  stageK(0, 0);                            // oldest: overlaps Q staging
  // ---- stage Q tile (16KB, register path) ----
#pragma unroll
  for (int i = 0; i < 2; ++i) {
    int c = tid + 512 * i;                 // 1024 16B-chunks
    int row = c >> 5, c16 = c & 31;
    *(f32x4*)(&sQ[row * 264 + c16 * 8]) =
        *(const f32x4*)(Qb + (size_t)(q0 + row) * 256 + c16 * 8);
  }
  __syncthreads();                         // Q + K tile 0 ready

  // ---- preload Q A-frags (rows wm*16+l15, both planes, 4 ksteps) ----
  bf16x8 qf[2][4];
  {
    const int row = wm * 16 + l15;
#pragma unroll
    for (int pl = 0; pl < 2; ++pl)
#pragma unroll
      for (int s = 0; s < 4; ++s)
        qf[pl][s] = *(const bf16x8*)(&sQ[row * 264 + pl * 128 + s * 32 + quad * 8]);
  }

  f32x4 O[2][2];
#pragma unroll
  for (int i = 0; i < 2; ++i)
#pragma unroll
    for (int j = 0; j < 2; ++j) O[i][j] = (f32x4){0.f, 0.f, 0.f, 0.f};
  float z[2][4] = {};

  const int kr = wk * 16 + l15;            // this wave's key row within tile

  for (int kt = 0; kt < nkt; ++kt) {
    const int k0 = kt << 6;
    const int buf = kt & 1;
    const bool needmask = (k0 + 63 > q0 + 1);

    // V frags for THIS tile: issued first (oldest VMEM of the iteration)
    bf16x8 vf[2][2];
#pragma unroll
    for (int nt = 0; nt < 2; ++nt)
#pragma unroll
      for (int ks = 0; ks < 2; ++ks)
        vf[nt][ks] = *(const bf16x8*)(Vtb + (size_t)(wk * 32 + nt * 16 + l15) * T_SEQ +
                                      k0 + ks * 32 + quad * 8);
    // stage NEXT K tile (younger than vf: PV's vf-wait leaves it in flight)
    if (kt + 1 < nkt) stageK(k0 + 64, buf ^ 1);

    // ---- QK^T from LDS (un-swizzle on read) ----
    f32x4 S[2];
#pragma unroll
    for (int mat = 0; mat < 2; ++mat) {
      S[mat] = (f32x4){0.f, 0.f, 0.f, 0.f};
#pragma unroll
      for (int s = 0; s < 4; ++s) {
        int cd = mat * 16 + s * 4 + quad;
        int slot = (cd & 24) | ((cd ^ kr) & 7);
        bf16x8 kfrag = *(const bf16x8*)(&sK[buf][(size_t)kr * 256 + slot * 8]);
        S[mat] = MFMA16(qf[mat][s], kfrag, S[mat], 0, 0, 0);
      }
    }

    // ---- exp + z partials + write P (bf16) to LDS ----
    const int rowl = wm * 16 + quad * 4;
    const int keyg = k0 + kr;
#pragma unroll
    for (int mat = 0; mat < 2; ++mat)
#pragma unroll
      for (int r = 0; r < 4; ++r) {
        float pv;
        if (needmask) {
          int rowg = q0 + rowl + r;
          pv = (keyg <= rowg + 1) ? __expf(S[mat][r] * SCALE) : 0.f;
        } else {
          pv = __expf(S[mat][r] * SCALE);
        }
        z[mat][r] += pv;
        sP[buf][mat][(rowl + r) * 72 + kr] = (__bf16)pv;
      }
    wg_barrier_lds();   // P visible; K staging stays in flight

    // ---- PV: O += P @ V (P from LDS, V from regs; counted vmcnt wait) ----
#pragma unroll
    for (int ks = 0; ks < 2; ++ks) {
      bf16x8 pf0 = *(const bf16x8*)(&sP[buf][0][(wm * 16 + l15) * 72 + ks * 32 + quad * 8]);
      bf16x8 pf1 = *(const bf16x8*)(&sP[buf][1][(wm * 16 + l15) * 72 + ks * 32 + quad * 8]);
#pragma unroll
      for (int nt = 0; nt < 2; ++nt) {
        O[0][nt] = MFMA16(pf0, vf[nt][ks], O[0][nt], 0, 0, 0);
        O[1][nt] = MFMA16(pf1, vf[nt][ks], O[1][nt], 0, 0, 0);
      }
    }
    __syncthreads();    // next tile ready (staging had ~full iteration)
  }

  // ---- Z reduction ----
#pragma unroll
  for (int mat = 0; mat < 2; ++mat)
#pragma unroll
    for (int r = 0; r < 4; ++r)
      zb[mat][wm * 16 + quad * 4 + r][wk * 16 + l15] = z[mat][r];
  __syncthreads();
  if (tid < 64) {
    int mat = tid >> 5, row = tid & 31;
    float s = 0.f;
#pragma unroll
    for (int j = 0; j < 64; ++j) s += zb[mat][row][(j + tid) & 63];  // bank-spread
    zfin[mat][row] = s;
  }
  __syncthreads();

  // ---- epilogue: normalize + closed-form masked tail + pad rows ----
#pragma unroll
  for (int r = 0; r < 4; ++r) {
    const int rowl = wm * 16 + quad * 4 + r;
    const int rowg = q0 + rowl;
    const int nallow = min(rowg + 2, T_SEQ);
    const float nmask = (float)(T_SEQ - nallow);
    const float Z1 = zfin[0][rowl] + nmask;
    const float Z2 = zfin[1][rowl] + nmask;
    const float i1 = 1.f / Z1, i2 = lbd / Z2;
    const float tc = i1 - i2;
    const bool isp = (pad[b * T_SEQ + rowg] == 1);
#pragma unroll
    for (int nt = 0; nt < 2; ++nt) {
      const int col = wk * 32 + nt * 16 + l15;
      const float ct = cumb[(size_t)T_SEQ * HS + col];
      const float cn = cumb[(size_t)nallow * HS + col];
      float val = isp ? (pc * ct)
                      : (O[0][nt][r] * i1 - O[1][nt][r] * i2 + tc * (ct - cn));
      out[((size_t)b * T_SEQ + rowg) * HS + col] = val;
    }
  }
}

// ---------------------------------------------------------------------------
extern "C" void kernel_launch(void* const* d_in, const int* in_sizes, int n_in,
                              void* d_out, int out_size, void* d_ws, size_t ws_size,
                              hipStream_t stream) {
  (void)in_sizes; (void)n_in; (void)out_size; (void)ws_size;
  const float* q   = (const float*)d_in[0];
  const float* k   = (const float*)d_in[1];
  const float* v   = (const float*)d_in[2];
  const int*   pm  = (const int*)d_in[3];
  const float* Wq  = (const float*)d_in[4];
  const float* Wk  = (const float*)d_in[5];
  const float* Wv  = (const float*)d_in[6];
  const float* lq1 = (const float*)d_in[7];
  const float* lk1 = (const float*)d_in[8];
  const float* lq2 = (const float*)d_in[9];
  const float* lk2 = (const float*)d_in[10];
  float* out = (float*)d_out;
  char* ws = (char*)d_ws;

  // workspace layout (bytes)
  float*  lbd  = (float*)ws;                                   // 16
  __bf16* Wp   = (__bf16*)(ws + 16);                           // 40*32*64*8*2 = 1310720
  __bf16* Qp   = (__bf16*)(ws + 16 + 1310720);                 // 8*2048*256*2
  __bf16* Kp   = Qp + (size_t)NB * T_SEQ * 256;
  __bf16* Vp   = Kp + (size_t)NB * T_SEQ * 256;                // 8*2048*128*2
  __bf16* Vt   = Vp + (size_t)NB * T_SEQ * HS;
  float*  cum  = (float*)(Vt + (size_t)NB * T_SEQ * HS);       // 8*2049*128*4
  float*  csum = cum + (size_t)NB * (T_SEQ + 1) * HS;          // 8*64*128*4

  lambda_kernel<<<dim3(1), dim3(128), 0, stream>>>(lq1, lk1, lq2, lk2, lbd);
  pack_w<<<dim3(40), dim3(256), 0, stream>>>(Wq, Wk, Wv, Wp);
  proj_mfma<<<dim3(768), dim3(128), 0, stream>>>(q, k, v, Wp, Qp, Kp, Vp, Vt);
  vcsum_a<<<dim3(512), dim3(128), 0, stream>>>(Vp, csum);
  vcsum_b<<<dim3(512), dim3(128), 0, stream>>>(Vp, csum, cum);
  attn_mfma<<<dim3(512), dim3(512), 0, stream>>>(Qp, Kp, Vt, cum, pm, lbd, out);
}